// Round 1
// 329.065 us; speedup vs baseline: 1.0494x; 1.0494x over previous
//
#include <hip/hip_runtime.h>
#include <hip/hip_bf16.h>

typedef short bf16x8 __attribute__((ext_vector_type(8)));
typedef short bf16x4 __attribute__((ext_vector_type(4)));
typedef float f32x4 __attribute__((ext_vector_type(4)));
typedef unsigned int u32;
typedef unsigned long long u64;

#define GLD_LDS16(gp, lp) \
  __builtin_amdgcn_global_load_lds((const __attribute__((address_space(1))) u32*)(gp), \
                                   (__attribute__((address_space(3))) u32*)(lp), 16, 0, 0)

__device__ __forceinline__ short f2bf(float f) {
  u32 u = __builtin_bit_cast(u32, f);
  u = (u + 0x7fffu + ((u >> 16) & 1u)) >> 16;
  return (short)u;
}

// gfx950 has no cvt_pk_bf16 builtin (m240) -- use the hardware op via inline asm.
// Single instruction replaces the ~9-op manual RNE fallback per pair.
__device__ __forceinline__ u32 pack2_bf16(float a, float b) {
#if __has_builtin(__builtin_amdgcn_cvt_pk_bf16_f32)
  typedef __bf16 bf16v2 __attribute__((ext_vector_type(2)));
  bf16v2 r = __builtin_amdgcn_cvt_pk_bf16_f32(a, b);
  return __builtin_bit_cast(u32, r);
#else
  u32 r;
  asm("v_cvt_pk_bf16_f32 %0, %1, %2" : "=v"(r) : "v"(a), "v"(b));
  return r;
#endif
}

__device__ __forceinline__ float exp2_fast(float x) {
#if __has_builtin(__builtin_amdgcn_exp2f)
  return __builtin_amdgcn_exp2f(x);
#else
  return exp2f(x);
#endif
}

// ---------------- small prep kernels ----------------

// one fused f32->bf16 conversion for hs (8192 blk) + Wqkv (3072 blk) + Wo (1024 blk)
__global__ __launch_bounds__(256) void cvt_all(
    const float* __restrict__ hs, const float* __restrict__ wqkv,
    const float* __restrict__ wo, short* __restrict__ xb,
    short* __restrict__ wqkvb, short* __restrict__ wob) {
  int b = blockIdx.x;
  const float* in;
  short* out;
  int base;
  if (b < 8192) {
    in = hs; out = xb; base = b * 1024;
  } else if (b < 8192 + 3072) {
    in = wqkv; out = wqkvb; base = (b - 8192) * 1024;
  } else {
    in = wo; out = wob; base = (b - 11264) * 1024;
  }
  int i = base + threadIdx.x * 4;
  float4 v = *(const float4*)(in + i);
  short4 o;
  o.x = f2bf(v.x); o.y = f2bf(v.y); o.z = f2bf(v.z); o.w = f2bf(v.w);
  *(short4*)(out + i) = o;
}

__global__ void rope_tables(const float* __restrict__ rpe, float* __restrict__ cosT,
                            float* __restrict__ sinT) {
  int i = blockIdx.x * 256 + threadIdx.x;  // 32768 = 1024*32
  float v = rpe[i];
  cosT[i] = cosf(v);
  sinT[i] = sinf(v);
}

// u64 bitmask per (b, q-row, key-tile-of-64): 1 MB total, L3-resident.
__global__ void mask_pack(const int* __restrict__ m, u64* __restrict__ out) {
  int i = blockIdx.x * 256 + threadIdx.x;  // 8*1024*1024 threads
  u64 bm = __ballot(m[i] != 0);
  if ((threadIdx.x & 63) == 0) out[i >> 6] = bm;
}

// ---------------- GEMM 1: QKV projection + bias + RoPE + scatter ----------------
// X (8192,1024) bf16, W (3072,1024) bf16; C = X * W^T. Tile 128x128, BK=32.
// MFMA operands SWAPPED (mfma(b,a)) so D row=channel, col=token: each lane holds
// 4 consecutive channels of one token -> in-register RoPE pairs, 8 B stores.
// q pre-scaled by 0.125 * log2(e) so flash softmax runs in exp2 domain.
__global__ __launch_bounds__(256, 2) void gemm_qkv(
    const short* __restrict__ Xb, const short* __restrict__ Wb,
    const float* __restrict__ bqkv, const float* __restrict__ cosT,
    const float* __restrict__ sinT, short* __restrict__ qb,
    short* __restrict__ kbuf, short* __restrict__ vbuf) {
  __shared__ short Ash[128 * 32];
  __shared__ short Bsh[128 * 32];
  const int tid = threadIdx.x;
  const int wid = tid >> 6, lane = tid & 63;
  const int g = lane >> 4, c = lane & 15;
  const int wm = wid >> 1, wn = wid & 1;
  const int m0 = blockIdx.y * 128, n0 = blockIdx.x * 128;

  f32x4 acc[4][4];
  for (int i = 0; i < 4; i++)
    for (int j = 0; j < 4; j++) acc[i][j] = (f32x4){0.f, 0.f, 0.f, 0.f};

  const int srow = lane >> 2;
  const int scol = (lane & 3) * 8;
  const short* AgL = Xb + (long)(m0 + wid * 32 + srow) * 1024 + scol;
  const short* BgL = Wb + (long)(n0 + wid * 32 + srow) * 1024 + scol;
  short* As0 = &Ash[(wid * 32) * 32];
  short* As1 = &Ash[(wid * 32 + 16) * 32];
  short* Bs0 = &Bsh[(wid * 32) * 32];
  short* Bs1 = &Bsh[(wid * 32 + 16) * 32];

  for (int kt = 0; kt < 32; ++kt) {
    const int ko = kt * 32;
    GLD_LDS16(AgL + ko, As0);
    GLD_LDS16(AgL + ko + 16 * 1024, As1);
    GLD_LDS16(BgL + ko, Bs0);
    GLD_LDS16(BgL + ko + 16 * 1024, Bs1);
    __syncthreads();
    bf16x8 af[4], bfr[4];
    for (int i = 0; i < 4; i++)
      af[i] = *(const bf16x8*)&Ash[(wm * 64 + i * 16 + c) * 32 + g * 8];
    for (int j = 0; j < 4; j++)
      bfr[j] = *(const bf16x8*)&Bsh[(wn * 64 + j * 16 + c) * 32 + g * 8];
    for (int i = 0; i < 4; i++)
      for (int j = 0; j < 4; j++)
        acc[i][j] = __builtin_amdgcn_mfma_f32_16x16x32_bf16(bfr[j], af[i], acc[i][j], 0, 0, 0);
    __syncthreads();
  }

  // epilogue: lane owns token r (col=c), 4 consecutive channels (rows=quad*4+reg)
  for (int jt = 0; jt < 4; jt++) {
    const int chan = n0 + wn * 64 + jt * 16 + g * 4;  // %4 == 0
    const int three = chan >> 10;
    const int hh = (chan >> 6) & 15;
    const int d = chan & 63;
    const float4 bq = *(const float4*)&bqkv[chan];
    for (int i = 0; i < 4; i++) {
      const int r = m0 + wm * 64 + i * 16 + c;
      const int l = r >> 3, b = r & 7;
      float v0 = acc[i][jt][0] + bq.x;
      float v1 = acc[i][jt][1] + bq.y;
      float v2 = acc[i][jt][2] + bq.z;
      float v3 = acc[i][jt][3] + bq.w;
      const long doff = ((long)(b * 16 + hh) * 1024 + l) * 64 + d;
      if (three == 2) {
        uint2 o = {pack2_bf16(v0, v1), pack2_bf16(v2, v3)};
        *(uint2*)&vbuf[doff] = o;
      } else {
        const float4 cs = *(const float4*)&cosT[l * 32 + (d & 31)];
        const float4 sn = *(const float4*)&sinT[l * 32 + (d & 31)];
        float e0 = v0 * cs.x - v1 * sn.x;
        float o0 = v1 * cs.y + v0 * sn.y;
        float e1 = v2 * cs.z - v3 * sn.z;
        float o1 = v3 * cs.w + v2 * sn.w;
        short* dst;
        if (three == 0) {
          const float S = 0.18033688011f;  // 1/sqrt(D) * log2(e)
          e0 *= S; o0 *= S; e1 *= S; o1 *= S;
          dst = qb;
        } else {
          dst = kbuf;
        }
        uint2 o = {pack2_bf16(e0, o0), pack2_bf16(e1, o1)};
        *(uint2*)&dst[doff] = o;
      }
    }
  }
}

// ---------------- V transpose: (B,H,L,D) -> (B,H,D,L) ----------------
__global__ __launch_bounds__(256) void transpose_v(const short* __restrict__ vbuf,
                                                   short* __restrict__ vTb) {
  __shared__ short T[64 * 72];
  const int bh = blockIdx.y;
  const int l0 = blockIdx.x * 64;
  const int t = threadIdx.x;
  const int row = t >> 3;
  const int cc = (t & 7) * 8;
  const short* src = vbuf + ((long)bh * 1024 + l0) * 64;
  for (int p = 0; p < 2; p++) {
    int lr = row + p * 32;
    *(bf16x8*)&T[lr * 72 + cc] = *(const bf16x8*)&src[(long)lr * 64 + cc];
  }
  __syncthreads();
  short* dst = vTb + (long)bh * 64 * 1024 + l0;
  for (int p = 0; p < 2; p++) {
    int d = row + p * 32;
    bf16x8 v;
    for (int j = 0; j < 8; j++) v[j] = T[(cc + j) * 72 + d];
    *(bf16x8*)&dst[(long)d * 1024 + cc] = v;
  }
}

// ---------------- flash attention v7 ----------------
// vs v6: (1) K rows staged PERMUTED (LDS row r <- key (r&32)|((r&15)>>2)<<3|
// ((r>>4)&1)<<2|(r&3)) so the QK^T z-registers of an nt-pair form a K=32
// B-operand directly -> PV + rowsum use mfma 16x16x32 (10 MFMAs vs 20 K=16:
// same FLOPs, half the issue slots); V fragments become 16B ds_reads.
// (2) T13 defer-max (THR=8 in exp2 domain): rescale + cross-lane max-reduce
// only when some lane exceeds m_run+8; P bounded by 2^8, fine in bf16.
// (3) pack2_bf16 is now one v_cvt_pk_bf16_f32.
__global__ __launch_bounds__(256, 5) void flash_attn(
    const short* __restrict__ qb, const short* __restrict__ kbuf,
    const short* __restrict__ vTb, const u64* __restrict__ maskb,
    short* __restrict__ attno) {
  __shared__ short K0[64 * 64], K1[64 * 64];
  __shared__ short V0[64 * 64], V1[64 * 64];
  const int t = threadIdx.x;
  const int wid = t >> 6, lane = t & 63;
  const int g = lane >> 4, c = lane & 15;
  const int q0 = blockIdx.x * 64;
  const int bh = blockIdx.y;
  const int b = bh >> 4;
  const int h = bh & 15;
  const long qoff = (long)bh * 1024 * 64;
  const int qrow = q0 + wid * 16 + c;  // this lane's q column

  // Q fragment (B-operand of S^T mfma)
  bf16x8 aq0, aq1;
  {
    const short* qp = qb + qoff + (long)qrow * 64;
    aq0 = *(const bf16x8*)(qp + g * 8);
    aq1 = *(const bf16x8*)(qp + 32 + g * 8);
  }

  f32x4 Od[4];
  for (int i = 0; i < 4; i++) Od[i] = (f32x4){0.f, 0.f, 0.f, 0.f};
  f32x4 Ld = (f32x4){0.f, 0.f, 0.f, 0.f};  // row-sum acc: D[0][q] = sum_k P[k][q]
  float m_run = -1e30f;

  // ones-row A-operand (K=32): lanes with m-index 0 hold bf16 1.0 across k
  bf16x8 avOnes8;
  {
    union { bf16x8 v; u32 u[4]; } av;
    u32 o1 = (c == 0) ? 0x3F803F80u : 0u;
    av.u[0] = av.u[1] = av.u[2] = av.u[3] = o1;
    avOnes8 = av.v;
  }

  const u64* mrow = maskb + ((long)b * 1024 + qrow) * 16;
  const short* Kg = kbuf + qoff;
  const short* Vg = vTb + qoff;

  // staging: wave w covers LDS rows w*16..w*16+15; lane l fetches global chunk
  // (l&7)^(l>>3) of its row -> lands at LDS chunk pos l&7 (xor swizzle).
  const int l8 = lane >> 3, l7 = lane & 7;
  const int sr = wid * 16 + l8;
  const int sch = ((l7 ^ l8) & 7) * 8;
  // K row permutation: LDS row r holds physical key phys(r) so that the z-reg
  // of (nt, g, reg) is physical key (nt>>1)*32 + g*8 + (nt&1)*4 + reg.
  const int r1 = wid * 16 + l8;
  const int r2 = r1 + 8;
  const int kp1 = (r1 & 32) | (((r1 & 15) >> 2) << 3) | (((r1 >> 4) & 1) << 2) | (r1 & 3);
  const int kp2 = (r2 & 32) | (((r2 & 15) >> 2) << 3) | (((r2 >> 4) & 1) << 2) | (r2 & 3);

  // fragment read offsets (shorts, within a 64x64 tile buffer)
  const int ck0 = g ^ (c & 7);
  const int kOff0 = c * 64 + ck0 * 8;
  const int kOff1 = c * 64 + (ck0 ^ 4) * 8;
  int vOff32[2];
  for (int kg = 0; kg < 2; kg++)
    vOff32[kg] = c * 64 + (((kg * 4 + g) ^ (c & 7)) * 8);

#define STAGE(KD, VD, ktn) do { \
    GLD_LDS16(Kg + (long)((ktn) + kp1) * 64 + sch,      &KD[(wid * 16) * 64]); \
    GLD_LDS16(Kg + (long)((ktn) + kp2) * 64 + sch,      &KD[(wid * 16 + 8) * 64]); \
    GLD_LDS16(Vg + (long)sr * 1024 + (ktn) + sch,       &VD[(wid * 16) * 64]); \
    GLD_LDS16(Vg + (long)(sr + 8) * 1024 + (ktn) + sch, &VD[(wid * 16 + 8) * 64]); \
  } while (0)

#define TILE(KB, VB, KP, VP, ki) do { \
    u64 mw = mrow[ki]; /* L3-resident, issued before the barrier */ \
    __syncthreads(); /* drains prefetch issued a full tile of compute ago */ \
    STAGE(KP, VP, (((ki) + 1) & 15) * 64); \
    f32x4 z[4]; \
    for (int nt = 0; nt < 4; nt++) { \
      bf16x8 bk0 = *(const bf16x8*)&KB[kOff0 + nt * 1024]; \
      bf16x8 bk1 = *(const bf16x8*)&KB[kOff1 + nt * 1024]; \
      f32x4 zz = (f32x4){0.f, 0.f, 0.f, 0.f}; \
      zz = __builtin_amdgcn_mfma_f32_16x16x32_bf16(bk0, aq0, zz, 0, 0, 0); \
      zz = __builtin_amdgcn_mfma_f32_16x16x32_bf16(bk1, aq1, zz, 0, 0, 0); \
      z[nt] = zz; \
    } \
    float mx = fmaxf(fmaxf(fmaxf(z[0][0], z[0][1]), fmaxf(z[0][2], z[0][3])), \
                     fmaxf(fmaxf(z[1][0], z[1][1]), fmaxf(z[1][2], z[1][3]))); \
    mx = fmaxf(mx, fmaxf(fmaxf(fmaxf(z[2][0], z[2][1]), fmaxf(z[2][2], z[2][3])), \
                         fmaxf(fmaxf(z[3][0], z[3][1]), fmaxf(z[3][2], z[3][3])))); \
    if (__ballot(mx > m_run + 8.f)) { /* rare after warm-up (T13) */ \
      mx = fmaxf(mx, __shfl_xor(mx, 16, 64)); \
      mx = fmaxf(mx, __shfl_xor(mx, 32, 64)); \
      float mnew = fmaxf(m_run, mx); \
      float al = exp2_fast(m_run - mnew); \
      for (int dt = 0; dt < 4; dt++) { \
        Od[dt][0] *= al; Od[dt][1] *= al; Od[dt][2] *= al; Od[dt][3] *= al; \
      } \
      Ld[0] *= al; \
      m_run = mnew; \
    } \
    for (int kg = 0; kg < 2; kg++) { \
      union { bf16x8 v; u32 u[4]; } pu; \
      for (int ntp = 0; ntp < 2; ntp++) { \
        const int nt = kg * 2 + ntp; \
        u32 m4 = (u32)(mw >> (kg * 32 + g * 8 + ntp * 4)) & 0xFu; \
        u32 mlo = ((m4 & 1u) ? 0xFFFFu : 0u) | ((m4 & 2u) ? 0xFFFF0000u : 0u); \
        u32 mhi = ((m4 & 4u) ? 0xFFFFu : 0u) | ((m4 & 8u) ? 0xFFFF0000u : 0u); \
        float p0 = exp2_fast(z[nt][0] - m_run); \
        float p1 = exp2_fast(z[nt][1] - m_run); \
        float p2 = exp2_fast(z[nt][2] - m_run); \
        float p3 = exp2_fast(z[nt][3] - m_run); \
        pu.u[ntp * 2 + 0] = pack2_bf16(p0, p1) & mlo; \
        pu.u[ntp * 2 + 1] = pack2_bf16(p2, p3) & mhi; \
      } \
      Ld = __builtin_amdgcn_mfma_f32_16x16x32_bf16(avOnes8, pu.v, Ld, 0, 0, 0); \
      for (int dt = 0; dt < 4; dt++) { \
        bf16x8 av = *(const bf16x8*)&VB[vOff32[kg] + dt * 1024]; \
        Od[dt] = __builtin_amdgcn_mfma_f32_16x16x32_bf16(av, pu.v, Od[dt], 0, 0, 0); \
      } \
    } \
  } while (0)

  STAGE(K0, V0, 0);
  for (int ki = 0; ki < 16; ki += 2) {
    TILE(K0, V0, K1, V1, ki);
    TILE(K1, V1, K0, V0, ki + 1);
  }
#undef TILE
#undef STAGE

  // l for q=c lives in lane c (reg 0 of quad 0); broadcast then normalize+store
  float lsum = __shfl(Ld[0], c, 64);
  float inv = 1.f / lsum;
  long rbase = ((long)qrow * 8 + b) * 1024 + h * 64 + g * 4;
  for (int dt = 0; dt < 4; dt++) {
    union { bf16x4 v; u32 u[2]; } o;
    o.u[0] = pack2_bf16(Od[dt][0] * inv, Od[dt][1] * inv);
    o.u[1] = pack2_bf16(Od[dt][2] * inv, Od[dt][3] * inv);
    *(bf16x4*)&attno[rbase + dt * 16] = o.v;
  }
}

// ---------------- GEMM 2: out = attno * Wo^T + bo (f32 out) ----------------
__global__ __launch_bounds__(256, 2) void gemm_out(
    const short* __restrict__ Ab, const short* __restrict__ Wob,
    const float* __restrict__ bo, float* __restrict__ out) {
  __shared__ short Ash[128 * 32];
  __shared__ short Bsh[128 * 32];
  const int tid = threadIdx.x;
  const int wid = tid >> 6, lane = tid & 63;
  const int g = lane >> 4, c = lane & 15;
  const int wm = wid >> 1, wn = wid & 1;
  const int m0 = blockIdx.y * 128, n0 = blockIdx.x * 128;

  f32x4 acc[4][4];
  for (int i = 0; i < 4; i++)
    for (int j = 0; j < 4; j++) acc[i][j] = (f32x4){0.f, 0.f, 0.f, 0.f};

  const int srow = lane >> 2;
  const int scol = (lane & 3) * 8;
  const short* AgL = Ab + (long)(m0 + wid * 32 + srow) * 1024 + scol;
  const short* BgL = Wob + (long)(n0 + wid * 32 + srow) * 1024 + scol;
  short* As0 = &Ash[(wid * 32) * 32];
  short* As1 = &Ash[(wid * 32 + 16) * 32];
  short* Bs0 = &Bsh[(wid * 32) * 32];
  short* Bs1 = &Bsh[(wid * 32 + 16) * 32];

  for (int kt = 0; kt < 32; ++kt) {
    const int ko = kt * 32;
    GLD_LDS16(AgL + ko, As0);
    GLD_LDS16(AgL + ko + 16 * 1024, As1);
    GLD_LDS16(BgL + ko, Bs0);
    GLD_LDS16(BgL + ko + 16 * 1024, Bs1);
    __syncthreads();
    bf16x8 af[4], bfr[4];
    for (int i = 0; i < 4; i++)
      af[i] = *(const bf16x8*)&Ash[(wm * 64 + i * 16 + c) * 32 + g * 8];
    for (int j = 0; j < 4; j++)
      bfr[j] = *(const bf16x8*)&Bsh[(wn * 64 + j * 16 + c) * 32 + g * 8];
    for (int i = 0; i < 4; i++)
      for (int j = 0; j < 4; j++)
        acc[i][j] = __builtin_amdgcn_mfma_f32_16x16x32_bf16(af[i], bfr[j], acc[i][j], 0, 0, 0);
    __syncthreads();
  }

  for (int jt = 0; jt < 4; jt++) {
    const int j = n0 + wn * 64 + jt * 16 + c;
    const float bias = bo[j];
    for (int i = 0; i < 4; i++) {
      const int rbase = m0 + wm * 64 + i * 16 + g * 4;
      for (int reg = 0; reg < 4; reg++)
        out[(long)(rbase + reg) * 1024 + j] = acc[i][jt][reg] + bias;
    }
  }
}

// ---------------- launcher ----------------
extern "C" void kernel_launch(void* const* d_in, const int* in_sizes, int n_in,
                              void* d_out, int out_size, void* d_ws, size_t ws_size,
                              hipStream_t stream) {
  const float* hs = (const float*)d_in[0];
  const float* rpe = (const float*)d_in[1];
  const int* amask = (const int*)d_in[2];
  const float* Wqkv = (const float*)d_in[3];
  const float* bqkv = (const float*)d_in[4];
  const float* Wo = (const float*)d_in[5];
  const float* bo = (const float*)d_in[6];
  float* out = (float*)d_out;

  char* ws = (char*)d_ws;
  auto alloc = [&](size_t bytes) {
    char* p = ws;
    ws += (bytes + 255) & ~(size_t)255;
    return p;
  };
  short* Xb = (short*)alloc(8192LL * 1024 * 2);
  short* Wqkvb = (short*)alloc(3072LL * 1024 * 2);
  short* Wob = (short*)alloc(1024LL * 1024 * 2);
  float* cosT = (float*)alloc(1024 * 32 * 4);
  float* sinT = (float*)alloc(1024 * 32 * 4);
  u64* maskb = (u64*)alloc(8LL * 1024 * 16 * 8);
  short* qb = (short*)alloc(128LL * 1024 * 64 * 2);
  short* kbuf = (short*)alloc(128LL * 1024 * 64 * 2);
  short* vbuf = (short*)alloc(128LL * 1024 * 64 * 2);
  short* vTb = (short*)alloc(128LL * 1024 * 64 * 2);
  short* attno = (short*)alloc(8192LL * 1024 * 2);

  cvt_all<<<12288, 256, 0, stream>>>(hs, Wqkv, Wo, Xb, Wqkvb, Wob);
  rope_tables<<<128, 256, 0, stream>>>(rpe, cosT, sinT);
  mask_pack<<<32768, 256, 0, stream>>>(amask, maskb);
  gemm_qkv<<<dim3(24, 64), 256, 0, stream>>>(Xb, Wqkvb, bqkv, cosT, sinT, qb, kbuf, vbuf);
  transpose_v<<<dim3(16, 128), 256, 0, stream>>>(vbuf, vTb);
  flash_attn<<<dim3(16, 128), 256, 0, stream>>>(qb, kbuf, vTb, maskb, attno);
  gemm_out<<<dim3(8, 64), 256, 0, stream>>>(attno, Wob, bo, out);
}

// Round 2
// 326.423 us; speedup vs baseline: 1.0579x; 1.0081x over previous
//
#include <hip/hip_runtime.h>
#include <hip/hip_bf16.h>

typedef short bf16x8 __attribute__((ext_vector_type(8)));
typedef short bf16x4 __attribute__((ext_vector_type(4)));
typedef float f32x4 __attribute__((ext_vector_type(4)));
typedef unsigned int u32;
typedef unsigned long long u64;

#define GLD_LDS16(gp, lp) \
  __builtin_amdgcn_global_load_lds((const __attribute__((address_space(1))) u32*)(gp), \
                                   (__attribute__((address_space(3))) u32*)(lp), 16, 0, 0)

__device__ __forceinline__ short f2bf(float f) {
  u32 u = __builtin_bit_cast(u32, f);
  u = (u + 0x7fffu + ((u >> 16) & 1u)) >> 16;
  return (short)u;
}

// gfx950 has no cvt_pk_bf16 builtin (m240) -- hardware op via inline asm.
__device__ __forceinline__ u32 pack2_bf16(float a, float b) {
#if __has_builtin(__builtin_amdgcn_cvt_pk_bf16_f32)
  typedef __bf16 bf16v2 __attribute__((ext_vector_type(2)));
  bf16v2 r = __builtin_amdgcn_cvt_pk_bf16_f32(a, b);
  return __builtin_bit_cast(u32, r);
#else
  u32 r;
  asm("v_cvt_pk_bf16_f32 %0, %1, %2" : "=v"(r) : "v"(a), "v"(b));
  return r;
#endif
}

__device__ __forceinline__ float exp2_fast(float x) {
#if __has_builtin(__builtin_amdgcn_exp2f)
  return __builtin_amdgcn_exp2f(x);
#else
  return exp2f(x);
#endif
}

// ---------------- small prep kernels ----------------

__global__ __launch_bounds__(256) void cvt_all(
    const float* __restrict__ hs, const float* __restrict__ wqkv,
    const float* __restrict__ wo, short* __restrict__ xb,
    short* __restrict__ wqkvb, short* __restrict__ wob) {
  int b = blockIdx.x;
  const float* in;
  short* out;
  int base;
  if (b < 8192) {
    in = hs; out = xb; base = b * 1024;
  } else if (b < 8192 + 3072) {
    in = wqkv; out = wqkvb; base = (b - 8192) * 1024;
  } else {
    in = wo; out = wob; base = (b - 11264) * 1024;
  }
  int i = base + threadIdx.x * 4;
  float4 v = *(const float4*)(in + i);
  short4 o;
  o.x = f2bf(v.x); o.y = f2bf(v.y); o.z = f2bf(v.z); o.w = f2bf(v.w);
  *(short4*)(out + i) = o;
}

__global__ void rope_tables(const float* __restrict__ rpe, float* __restrict__ cosT,
                            float* __restrict__ sinT) {
  int i = blockIdx.x * 256 + threadIdx.x;  // 32768 = 1024*32
  float v = rpe[i];
  cosT[i] = cosf(v);
  sinT[i] = sinf(v);
}

__global__ void mask_pack(const int* __restrict__ m, u64* __restrict__ out) {
  int i = blockIdx.x * 256 + threadIdx.x;  // 8*1024*1024 threads
  u64 bm = __ballot(m[i] != 0);
  if ((threadIdx.x & 63) == 0) out[i >> 6] = bm;
}

// ---------------- GEMM 1: QKV projection + bias + RoPE + scatter ----------------
// v2: double-buffered LDS + prefetch-next-tile + counted s_waitcnt vmcnt(4) with raw
// s_barrier (T3-min/T4); XOR bank swizzle on fragment slots (slot = g ^ ((row>>1)&3),
// source-side pre-permuted so global_load_lds dest stays linear, rule #21);
// occupancy 2 -> 4 blocks/CU. Operands swapped (mfma(b,a)) so D row=channel, col=token.
__global__ __launch_bounds__(256, 4) void gemm_qkv(
    const short* __restrict__ Xb, const short* __restrict__ Wb,
    const float* __restrict__ bqkv, const float* __restrict__ cosT,
    const float* __restrict__ sinT, short* __restrict__ qb,
    short* __restrict__ kbuf, short* __restrict__ vbuf) {
  __shared__ short Ash[2][128 * 32];
  __shared__ short Bsh[2][128 * 32];
  const int tid = threadIdx.x;
  const int wid = tid >> 6, lane = tid & 63;
  const int g = lane >> 4, c = lane & 15;
  const int wm = wid >> 1, wn = wid & 1;
  const int m0 = blockIdx.y * 128, n0 = blockIdx.x * 128;

  f32x4 acc[4][4];
  for (int i = 0; i < 4; i++)
    for (int j = 0; j < 4; j++) acc[i][j] = (f32x4){0.f, 0.f, 0.f, 0.f};

  // staging: lane l -> LDS row (slab + l>>2), 16B slot l&3 (linear dest).
  // source chunk pre-swizzled: (l&3) ^ f(row), f(row) = (row>>1)&3 = (l>>3)&3.
  const int srow = lane >> 2;
  const int scol = ((lane & 3) ^ ((lane >> 3) & 3)) * 8;
  const short* AgL = Xb + (long)(m0 + wid * 32 + srow) * 1024 + scol;
  const short* BgL = Wb + (long)(n0 + wid * 32 + srow) * 1024 + scol;
  const int dst0 = (wid * 32) * 32;
  const int dst1 = (wid * 32 + 16) * 32;
  // fragment read slot: rows wm*64+i*16+c -> f(row) = (c>>1)&3 (lane-constant)
  const int ck = g ^ ((c >> 1) & 3);

#define QKV_KSTEP(CA, CB, PA, PB, nko) do { \
    GLD_LDS16(AgL + (nko), &(PA)[dst0]); \
    GLD_LDS16(AgL + (nko) + 16 * 1024, &(PA)[dst1]); \
    GLD_LDS16(BgL + (nko), &(PB)[dst0]); \
    GLD_LDS16(BgL + (nko) + 16 * 1024, &(PB)[dst1]); \
    asm volatile("s_waitcnt vmcnt(4)" ::: "memory"); \
    __builtin_amdgcn_s_barrier(); \
    __builtin_amdgcn_sched_barrier(0); \
    bf16x8 af[4], bfr[4]; \
    for (int i = 0; i < 4; i++) \
      af[i] = *(const bf16x8*)&(CA)[(wm * 64 + i * 16 + c) * 32 + ck * 8]; \
    for (int j = 0; j < 4; j++) \
      bfr[j] = *(const bf16x8*)&(CB)[(wn * 64 + j * 16 + c) * 32 + ck * 8]; \
    for (int i = 0; i < 4; i++) \
      for (int j = 0; j < 4; j++) \
        acc[i][j] = __builtin_amdgcn_mfma_f32_16x16x32_bf16(bfr[j], af[i], acc[i][j], 0, 0, 0); \
    __builtin_amdgcn_sched_barrier(0); \
    __builtin_amdgcn_s_barrier(); \
  } while (0)

  GLD_LDS16(AgL, &Ash[0][dst0]);
  GLD_LDS16(AgL + 16 * 1024, &Ash[0][dst1]);
  GLD_LDS16(BgL, &Bsh[0][dst0]);
  GLD_LDS16(BgL + 16 * 1024, &Bsh[0][dst1]);
  for (int kt = 0; kt < 32; kt += 2) {
    QKV_KSTEP(Ash[0], Bsh[0], Ash[1], Bsh[1], (kt + 1) * 32);
    QKV_KSTEP(Ash[1], Bsh[1], Ash[0], Bsh[0], ((kt + 2) & 31) * 32);
  }
#undef QKV_KSTEP

  // epilogue: lane owns token r (col=c), 4 consecutive channels (rows=quad*4+reg)
  for (int jt = 0; jt < 4; jt++) {
    const int chan = n0 + wn * 64 + jt * 16 + g * 4;  // %4 == 0
    const int three = chan >> 10;
    const int hh = (chan >> 6) & 15;
    const int d = chan & 63;
    const float4 bq = *(const float4*)&bqkv[chan];
    for (int i = 0; i < 4; i++) {
      const int r = m0 + wm * 64 + i * 16 + c;
      const int l = r >> 3, b = r & 7;
      float v0 = acc[i][jt][0] + bq.x;
      float v1 = acc[i][jt][1] + bq.y;
      float v2 = acc[i][jt][2] + bq.z;
      float v3 = acc[i][jt][3] + bq.w;
      const long doff = ((long)(b * 16 + hh) * 1024 + l) * 64 + d;
      if (three == 2) {
        uint2 o = {pack2_bf16(v0, v1), pack2_bf16(v2, v3)};
        *(uint2*)&vbuf[doff] = o;
      } else {
        const float4 cs = *(const float4*)&cosT[l * 32 + (d & 31)];
        const float4 sn = *(const float4*)&sinT[l * 32 + (d & 31)];
        float e0 = v0 * cs.x - v1 * sn.x;
        float o0 = v1 * cs.y + v0 * sn.y;
        float e1 = v2 * cs.z - v3 * sn.z;
        float o1 = v3 * cs.w + v2 * sn.w;
        short* dst;
        if (three == 0) {
          const float S = 0.18033688011f;  // 1/sqrt(D) * log2(e)
          e0 *= S; o0 *= S; e1 *= S; o1 *= S;
          dst = qb;
        } else {
          dst = kbuf;
        }
        uint2 o = {pack2_bf16(e0, o0), pack2_bf16(e1, o1)};
        *(uint2*)&dst[doff] = o;
      }
    }
  }
}

// ---------------- V transpose: (B,H,L,D) -> (B,H,D,L) ----------------
__global__ __launch_bounds__(256) void transpose_v(const short* __restrict__ vbuf,
                                                   short* __restrict__ vTb) {
  __shared__ short T[64 * 72];
  const int bh = blockIdx.y;
  const int l0 = blockIdx.x * 64;
  const int t = threadIdx.x;
  const int row = t >> 3;
  const int cc = (t & 7) * 8;
  const short* src = vbuf + ((long)bh * 1024 + l0) * 64;
  for (int p = 0; p < 2; p++) {
    int lr = row + p * 32;
    *(bf16x8*)&T[lr * 72 + cc] = *(const bf16x8*)&src[(long)lr * 64 + cc];
  }
  __syncthreads();
  short* dst = vTb + (long)bh * 64 * 1024 + l0;
  for (int p = 0; p < 2; p++) {
    int d = row + p * 32;
    bf16x8 v;
    for (int j = 0; j < 8; j++) v[j] = T[(cc + j) * 72 + d];
    *(bf16x8*)&dst[(long)d * 1024 + cc] = v;
  }
}

// ---------------- flash attention v7 (unchanged from round 1) ----------------
__global__ __launch_bounds__(256, 5) void flash_attn(
    const short* __restrict__ qb, const short* __restrict__ kbuf,
    const short* __restrict__ vTb, const u64* __restrict__ maskb,
    short* __restrict__ attno) {
  __shared__ short K0[64 * 64], K1[64 * 64];
  __shared__ short V0[64 * 64], V1[64 * 64];
  const int t = threadIdx.x;
  const int wid = t >> 6, lane = t & 63;
  const int g = lane >> 4, c = lane & 15;
  const int q0 = blockIdx.x * 64;
  const int bh = blockIdx.y;
  const int b = bh >> 4;
  const int h = bh & 15;
  const long qoff = (long)bh * 1024 * 64;
  const int qrow = q0 + wid * 16 + c;  // this lane's q column

  // Q fragment (B-operand of S^T mfma)
  bf16x8 aq0, aq1;
  {
    const short* qp = qb + qoff + (long)qrow * 64;
    aq0 = *(const bf16x8*)(qp + g * 8);
    aq1 = *(const bf16x8*)(qp + 32 + g * 8);
  }

  f32x4 Od[4];
  for (int i = 0; i < 4; i++) Od[i] = (f32x4){0.f, 0.f, 0.f, 0.f};
  f32x4 Ld = (f32x4){0.f, 0.f, 0.f, 0.f};  // row-sum acc: D[0][q] = sum_k P[k][q]
  float m_run = -1e30f;

  // ones-row A-operand (K=32): lanes with m-index 0 hold bf16 1.0 across k
  bf16x8 avOnes8;
  {
    union { bf16x8 v; u32 u[4]; } av;
    u32 o1 = (c == 0) ? 0x3F803F80u : 0u;
    av.u[0] = av.u[1] = av.u[2] = av.u[3] = o1;
    avOnes8 = av.v;
  }

  const u64* mrow = maskb + ((long)b * 1024 + qrow) * 16;
  const short* Kg = kbuf + qoff;
  const short* Vg = vTb + qoff;

  const int l8 = lane >> 3, l7 = lane & 7;
  const int sr = wid * 16 + l8;
  const int sch = ((l7 ^ l8) & 7) * 8;
  // K row permutation: LDS row r holds physical key phys(r) so that the z-reg
  // of (nt, g, reg) is physical key (nt>>1)*32 + g*8 + (nt&1)*4 + reg.
  const int r1 = wid * 16 + l8;
  const int r2 = r1 + 8;
  const int kp1 = (r1 & 32) | (((r1 & 15) >> 2) << 3) | (((r1 >> 4) & 1) << 2) | (r1 & 3);
  const int kp2 = (r2 & 32) | (((r2 & 15) >> 2) << 3) | (((r2 >> 4) & 1) << 2) | (r2 & 3);

  const int ck0 = g ^ (c & 7);
  const int kOff0 = c * 64 + ck0 * 8;
  const int kOff1 = c * 64 + (ck0 ^ 4) * 8;
  int vOff32[2];
  for (int kg = 0; kg < 2; kg++)
    vOff32[kg] = c * 64 + (((kg * 4 + g) ^ (c & 7)) * 8);

#define STAGE(KD, VD, ktn) do { \
    GLD_LDS16(Kg + (long)((ktn) + kp1) * 64 + sch,      &KD[(wid * 16) * 64]); \
    GLD_LDS16(Kg + (long)((ktn) + kp2) * 64 + sch,      &KD[(wid * 16 + 8) * 64]); \
    GLD_LDS16(Vg + (long)sr * 1024 + (ktn) + sch,       &VD[(wid * 16) * 64]); \
    GLD_LDS16(Vg + (long)(sr + 8) * 1024 + (ktn) + sch, &VD[(wid * 16 + 8) * 64]); \
  } while (0)

#define TILE(KB, VB, KP, VP, ki) do { \
    u64 mw = mrow[ki]; /* L3-resident, issued before the barrier */ \
    __syncthreads(); /* drains prefetch issued a full tile of compute ago */ \
    STAGE(KP, VP, (((ki) + 1) & 15) * 64); \
    f32x4 z[4]; \
    for (int nt = 0; nt < 4; nt++) { \
      bf16x8 bk0 = *(const bf16x8*)&KB[kOff0 + nt * 1024]; \
      bf16x8 bk1 = *(const bf16x8*)&KB[kOff1 + nt * 1024]; \
      f32x4 zz = (f32x4){0.f, 0.f, 0.f, 0.f}; \
      zz = __builtin_amdgcn_mfma_f32_16x16x32_bf16(bk0, aq0, zz, 0, 0, 0); \
      zz = __builtin_amdgcn_mfma_f32_16x16x32_bf16(bk1, aq1, zz, 0, 0, 0); \
      z[nt] = zz; \
    } \
    float mx = fmaxf(fmaxf(fmaxf(z[0][0], z[0][1]), fmaxf(z[0][2], z[0][3])), \
                     fmaxf(fmaxf(z[1][0], z[1][1]), fmaxf(z[1][2], z[1][3]))); \
    mx = fmaxf(mx, fmaxf(fmaxf(fmaxf(z[2][0], z[2][1]), fmaxf(z[2][2], z[2][3])), \
                         fmaxf(fmaxf(z[3][0], z[3][1]), fmaxf(z[3][2], z[3][3])))); \
    if (__ballot(mx > m_run + 8.f)) { /* rare after warm-up (T13) */ \
      mx = fmaxf(mx, __shfl_xor(mx, 16, 64)); \
      mx = fmaxf(mx, __shfl_xor(mx, 32, 64)); \
      float mnew = fmaxf(m_run, mx); \
      float al = exp2_fast(m_run - mnew); \
      for (int dt = 0; dt < 4; dt++) { \
        Od[dt][0] *= al; Od[dt][1] *= al; Od[dt][2] *= al; Od[dt][3] *= al; \
      } \
      Ld[0] *= al; \
      m_run = mnew; \
    } \
    for (int kg = 0; kg < 2; kg++) { \
      union { bf16x8 v; u32 u[4]; } pu; \
      for (int ntp = 0; ntp < 2; ntp++) { \
        const int nt = kg * 2 + ntp; \
        u32 m4 = (u32)(mw >> (kg * 32 + g * 8 + ntp * 4)) & 0xFu; \
        u32 mlo = ((m4 & 1u) ? 0xFFFFu : 0u) | ((m4 & 2u) ? 0xFFFF0000u : 0u); \
        u32 mhi = ((m4 & 4u) ? 0xFFFFu : 0u) | ((m4 & 8u) ? 0xFFFF0000u : 0u); \
        float p0 = exp2_fast(z[nt][0] - m_run); \
        float p1 = exp2_fast(z[nt][1] - m_run); \
        float p2 = exp2_fast(z[nt][2] - m_run); \
        float p3 = exp2_fast(z[nt][3] - m_run); \
        pu.u[ntp * 2 + 0] = pack2_bf16(p0, p1) & mlo; \
        pu.u[ntp * 2 + 1] = pack2_bf16(p2, p3) & mhi; \
      } \
      Ld = __builtin_amdgcn_mfma_f32_16x16x32_bf16(avOnes8, pu.v, Ld, 0, 0, 0); \
      for (int dt = 0; dt < 4; dt++) { \
        bf16x8 av = *(const bf16x8*)&VB[vOff32[kg] + dt * 1024]; \
        Od[dt] = __builtin_amdgcn_mfma_f32_16x16x32_bf16(av, pu.v, Od[dt], 0, 0, 0); \
      } \
    } \
  } while (0)

  STAGE(K0, V0, 0);
  for (int ki = 0; ki < 16; ki += 2) {
    TILE(K0, V0, K1, V1, ki);
    TILE(K1, V1, K0, V0, ki + 1);
  }
#undef TILE
#undef STAGE

  float lsum = __shfl(Ld[0], c, 64);
  float inv = 1.f / lsum;
  long rbase = ((long)qrow * 8 + b) * 1024 + h * 64 + g * 4;
  for (int dt = 0; dt < 4; dt++) {
    union { bf16x4 v; u32 u[2]; } o;
    o.u[0] = pack2_bf16(Od[dt][0] * inv, Od[dt][1] * inv);
    o.u[1] = pack2_bf16(Od[dt][2] * inv, Od[dt][3] * inv);
    *(bf16x4*)&attno[rbase + dt * 16] = o.v;
  }
}

// ---------------- GEMM 2: out = attno * Wo^T + bo (f32 out) ----------------
// v2: same dbuf + counted-vmcnt + XOR-swizzle + occupancy-4 as gemm_qkv.
__global__ __launch_bounds__(256, 4) void gemm_out(
    const short* __restrict__ Ab, const short* __restrict__ Wob,
    const float* __restrict__ bo, float* __restrict__ out) {
  __shared__ short Ash[2][128 * 32];
  __shared__ short Bsh[2][128 * 32];
  const int tid = threadIdx.x;
  const int wid = tid >> 6, lane = tid & 63;
  const int g = lane >> 4, c = lane & 15;
  const int wm = wid >> 1, wn = wid & 1;
  const int m0 = blockIdx.y * 128, n0 = blockIdx.x * 128;

  f32x4 acc[4][4];
  for (int i = 0; i < 4; i++)
    for (int j = 0; j < 4; j++) acc[i][j] = (f32x4){0.f, 0.f, 0.f, 0.f};

  const int srow = lane >> 2;
  const int scol = ((lane & 3) ^ ((lane >> 3) & 3)) * 8;
  const short* AgL = Ab + (long)(m0 + wid * 32 + srow) * 1024 + scol;
  const short* BgL = Wob + (long)(n0 + wid * 32 + srow) * 1024 + scol;
  const int dst0 = (wid * 32) * 32;
  const int dst1 = (wid * 32 + 16) * 32;
  const int ck = g ^ ((c >> 1) & 3);

#define OUT_KSTEP(CA, CB, PA, PB, nko) do { \
    GLD_LDS16(AgL + (nko), &(PA)[dst0]); \
    GLD_LDS16(AgL + (nko) + 16 * 1024, &(PA)[dst1]); \
    GLD_LDS16(BgL + (nko), &(PB)[dst0]); \
    GLD_LDS16(BgL + (nko) + 16 * 1024, &(PB)[dst1]); \
    asm volatile("s_waitcnt vmcnt(4)" ::: "memory"); \
    __builtin_amdgcn_s_barrier(); \
    __builtin_amdgcn_sched_barrier(0); \
    bf16x8 af[4], bfr[4]; \
    for (int i = 0; i < 4; i++) \
      af[i] = *(const bf16x8*)&(CA)[(wm * 64 + i * 16 + c) * 32 + ck * 8]; \
    for (int j = 0; j < 4; j++) \
      bfr[j] = *(const bf16x8*)&(CB)[(wn * 64 + j * 16 + c) * 32 + ck * 8]; \
    for (int i = 0; i < 4; i++) \
      for (int j = 0; j < 4; j++) \
        acc[i][j] = __builtin_amdgcn_mfma_f32_16x16x32_bf16(af[i], bfr[j], acc[i][j], 0, 0, 0); \
    __builtin_amdgcn_sched_barrier(0); \
    __builtin_amdgcn_s_barrier(); \
  } while (0)

  GLD_LDS16(AgL, &Ash[0][dst0]);
  GLD_LDS16(AgL + 16 * 1024, &Ash[0][dst1]);
  GLD_LDS16(BgL, &Bsh[0][dst0]);
  GLD_LDS16(BgL + 16 * 1024, &Bsh[0][dst1]);
  for (int kt = 0; kt < 32; kt += 2) {
    OUT_KSTEP(Ash[0], Bsh[0], Ash[1], Bsh[1], (kt + 1) * 32);
    OUT_KSTEP(Ash[1], Bsh[1], Ash[0], Bsh[0], ((kt + 2) & 31) * 32);
  }
#undef OUT_KSTEP

  for (int jt = 0; jt < 4; jt++) {
    const int j = n0 + wn * 64 + jt * 16 + c;
    const float bias = bo[j];
    for (int i = 0; i < 4; i++) {
      const int rbase = m0 + wm * 64 + i * 16 + g * 4;
      for (int reg = 0; reg < 4; reg++)
        out[(long)(rbase + reg) * 1024 + j] = acc[i][jt][reg] + bias;
    }
  }
}

// ---------------- launcher ----------------
extern "C" void kernel_launch(void* const* d_in, const int* in_sizes, int n_in,
                              void* d_out, int out_size, void* d_ws, size_t ws_size,
                              hipStream_t stream) {
  const float* hs = (const float*)d_in[0];
  const float* rpe = (const float*)d_in[1];
  const int* amask = (const int*)d_in[2];
  const float* Wqkv = (const float*)d_in[3];
  const float* bqkv = (const float*)d_in[4];
  const float* Wo = (const float*)d_in[5];
  const float* bo = (const float*)d_in[6];
  float* out = (float*)d_out;

  char* ws = (char*)d_ws;
  auto alloc = [&](size_t bytes) {
    char* p = ws;
    ws += (bytes + 255) & ~(size_t)255;
    return p;
  };
  short* Xb = (short*)alloc(8192LL * 1024 * 2);
  short* Wqkvb = (short*)alloc(3072LL * 1024 * 2);
  short* Wob = (short*)alloc(1024LL * 1024 * 2);
  float* cosT = (float*)alloc(1024 * 32 * 4);
  float* sinT = (float*)alloc(1024 * 32 * 4);
  u64* maskb = (u64*)alloc(8LL * 1024 * 16 * 8);
  short* qb = (short*)alloc(128LL * 1024 * 64 * 2);
  short* kbuf = (short*)alloc(128LL * 1024 * 64 * 2);
  short* vbuf = (short*)alloc(128LL * 1024 * 64 * 2);
  short* vTb = (short*)alloc(128LL * 1024 * 64 * 2);
  short* attno = (short*)alloc(8192LL * 1024 * 2);

  cvt_all<<<12288, 256, 0, stream>>>(hs, Wqkv, Wo, Xb, Wqkvb, Wob);
  rope_tables<<<128, 256, 0, stream>>>(rpe, cosT, sinT);
  mask_pack<<<32768, 256, 0, stream>>>(amask, maskb);
  gemm_qkv<<<dim3(24, 64), 256, 0, stream>>>(Xb, Wqkvb, bqkv, cosT, sinT, qb, kbuf, vbuf);
  transpose_v<<<dim3(16, 128), 256, 0, stream>>>(vbuf, vTb);
  flash_attn<<<dim3(16, 128), 256, 0, stream>>>(qb, kbuf, vTb, maskb, attno);
  gemm_out<<<dim3(8, 64), 256, 0, stream>>>(attno, Wob, bo, out);
}

// Round 3
// 314.299 us; speedup vs baseline: 1.0987x; 1.0386x over previous
//
#include <hip/hip_runtime.h>
#include <hip/hip_bf16.h>

typedef short bf16x8 __attribute__((ext_vector_type(8)));
typedef short bf16x4 __attribute__((ext_vector_type(4)));
typedef float f32x4 __attribute__((ext_vector_type(4)));
typedef unsigned int u32;
typedef unsigned long long u64;

#define GLD_LDS16(gp, lp) \
  __builtin_amdgcn_global_load_lds((const __attribute__((address_space(1))) u32*)(gp), \
                                   (__attribute__((address_space(3))) u32*)(lp), 16, 0, 0)

__device__ __forceinline__ short f2bf(float f) {
  u32 u = __builtin_bit_cast(u32, f);
  u = (u + 0x7fffu + ((u >> 16) & 1u)) >> 16;
  return (short)u;
}

// gfx950 has no cvt_pk_bf16 builtin (m240) -- hardware op via inline asm.
__device__ __forceinline__ u32 pack2_bf16(float a, float b) {
#if __has_builtin(__builtin_amdgcn_cvt_pk_bf16_f32)
  typedef __bf16 bf16v2 __attribute__((ext_vector_type(2)));
  bf16v2 r = __builtin_amdgcn_cvt_pk_bf16_f32(a, b);
  return __builtin_bit_cast(u32, r);
#else
  u32 r;
  asm("v_cvt_pk_bf16_f32 %0, %1, %2" : "=v"(r) : "v"(a), "v"(b));
  return r;
#endif
}

__device__ __forceinline__ float exp2_fast(float x) {
#if __has_builtin(__builtin_amdgcn_exp2f)
  return __builtin_amdgcn_exp2f(x);
#else
  return exp2f(x);
#endif
}

// ---------------- fused prep: mask_pack (32768 blk) + cvt (12288 blk) + rope (128 blk) ----
__global__ __launch_bounds__(256) void prep_all(
    const int* __restrict__ m, u64* __restrict__ maskb,
    const float* __restrict__ hs, const float* __restrict__ wqkv,
    const float* __restrict__ wo, short* __restrict__ xb,
    short* __restrict__ wqkvb, short* __restrict__ wob,
    const float* __restrict__ rpe, float* __restrict__ cosT,
    float* __restrict__ sinT) {
  int b = blockIdx.x;
  if (b < 32768) {
    int i = b * 256 + threadIdx.x;
    u64 bm = __ballot(m[i] != 0);
    if ((threadIdx.x & 63) == 0) maskb[i >> 6] = bm;
    return;
  }
  b -= 32768;
  if (b < 12288) {
    const float* in;
    short* out;
    int base;
    if (b < 8192) {
      in = hs; out = xb; base = b * 1024;
    } else if (b < 8192 + 3072) {
      in = wqkv; out = wqkvb; base = (b - 8192) * 1024;
    } else {
      in = wo; out = wob; base = (b - 11264) * 1024;
    }
    int i = base + threadIdx.x * 4;
    float4 v = *(const float4*)(in + i);
    short4 o;
    o.x = f2bf(v.x); o.y = f2bf(v.y); o.z = f2bf(v.z); o.w = f2bf(v.w);
    *(short4*)(out + i) = o;
    return;
  }
  b -= 12288;
  int i = b * 256 + threadIdx.x;  // 32768 = 1024*32
  float v = rpe[i];
  cosT[i] = cosf(v);
  sinT[i] = sinf(v);
}

// ---------------- GEMM 1: QKV projection + bias + RoPE + scatter ----------------
// v3: T3-minimum single-barrier K-step (STAGE next; ds_read cur; MFMA; __syncthreads)
// -- wait sits AFTER compute, one rendezvous per step. Dbuf LDS 32KB, (256,4) = up to
// 4 blocks/CU. XOR bank swizzle kept (conflicts=0 verified r2). XCD-aware bijective
// block swizzle (T1, 1536%8==0) for L2 panel locality -> fewer HBM-latency stalls.
__global__ __launch_bounds__(256, 4) void gemm_qkv(
    const short* __restrict__ Xb, const short* __restrict__ Wb,
    const float* __restrict__ bqkv, const float* __restrict__ cosT,
    const float* __restrict__ sinT, short* __restrict__ qb,
    short* __restrict__ kbuf, short* __restrict__ vbuf) {
  __shared__ short Ash[2][128 * 32];
  __shared__ short Bsh[2][128 * 32];
  const int tid = threadIdx.x;
  const int wid = tid >> 6, lane = tid & 63;
  const int g = lane >> 4, c = lane & 15;
  const int wm = wid >> 1, wn = wid & 1;
  // XCD swizzle: nwg=1536 (24x64), 192 contiguous tiles per XCD
  const int bid = blockIdx.y * 24 + blockIdx.x;
  const int swz = (bid & 7) * 192 + (bid >> 3);
  const int m0 = (swz / 24) * 128, n0 = (swz % 24) * 128;

  f32x4 acc[4][4];
  for (int i = 0; i < 4; i++)
    for (int j = 0; j < 4; j++) acc[i][j] = (f32x4){0.f, 0.f, 0.f, 0.f};

  // staging: lane l -> LDS row (slab + l>>2), 16B slot l&3 (linear dest).
  // source chunk pre-swizzled: (l&3) ^ ((l>>3)&3) so fragment reads are 2-way max.
  const int srow = lane >> 2;
  const int scol = ((lane & 3) ^ ((lane >> 3) & 3)) * 8;
  const short* AgL = Xb + (long)(m0 + wid * 32 + srow) * 1024 + scol;
  const short* BgL = Wb + (long)(n0 + wid * 32 + srow) * 1024 + scol;
  const int dst0 = (wid * 32) * 32;
  const int dst1 = (wid * 32 + 16) * 32;
  const int ck = g ^ ((c >> 1) & 3);

#define QKV_STAGE(PA, PB, nko) do { \
    GLD_LDS16(AgL + (nko), &(PA)[dst0]); \
    GLD_LDS16(AgL + (nko) + 16 * 1024, &(PA)[dst1]); \
    GLD_LDS16(BgL + (nko), &(PB)[dst0]); \
    GLD_LDS16(BgL + (nko) + 16 * 1024, &(PB)[dst1]); \
  } while (0)

#define QKV_COMPUTE(CA, CB) do { \
    bf16x8 af[4], bfr[4]; \
    for (int i = 0; i < 4; i++) \
      af[i] = *(const bf16x8*)&(CA)[(wm * 64 + i * 16 + c) * 32 + ck * 8]; \
    for (int j = 0; j < 4; j++) \
      bfr[j] = *(const bf16x8*)&(CB)[(wn * 64 + j * 16 + c) * 32 + ck * 8]; \
    for (int i = 0; i < 4; i++) \
      for (int j = 0; j < 4; j++) \
        acc[i][j] = __builtin_amdgcn_mfma_f32_16x16x32_bf16(bfr[j], af[i], acc[i][j], 0, 0, 0); \
  } while (0)

  QKV_STAGE(Ash[0], Bsh[0], 0);
  __syncthreads();
  for (int kt = 0; kt < 32; kt += 2) {
    QKV_STAGE(Ash[1], Bsh[1], (kt + 1) * 32);
    QKV_COMPUTE(Ash[0], Bsh[0]);
    __syncthreads();
    if (kt + 2 < 32) QKV_STAGE(Ash[0], Bsh[0], (kt + 2) * 32);
    QKV_COMPUTE(Ash[1], Bsh[1]);
    __syncthreads();
  }
#undef QKV_STAGE
#undef QKV_COMPUTE

  // epilogue: lane owns token r (col=c), 4 consecutive channels (rows=quad*4+reg)
  for (int jt = 0; jt < 4; jt++) {
    const int chan = n0 + wn * 64 + jt * 16 + g * 4;  // %4 == 0
    const int three = chan >> 10;
    const int hh = (chan >> 6) & 15;
    const int d = chan & 63;
    const float4 bq = *(const float4*)&bqkv[chan];
    for (int i = 0; i < 4; i++) {
      const int r = m0 + wm * 64 + i * 16 + c;
      const int l = r >> 3, b = r & 7;
      float v0 = acc[i][jt][0] + bq.x;
      float v1 = acc[i][jt][1] + bq.y;
      float v2 = acc[i][jt][2] + bq.z;
      float v3 = acc[i][jt][3] + bq.w;
      const long doff = ((long)(b * 16 + hh) * 1024 + l) * 64 + d;
      if (three == 2) {
        uint2 o = {pack2_bf16(v0, v1), pack2_bf16(v2, v3)};
        *(uint2*)&vbuf[doff] = o;
      } else {
        const float4 cs = *(const float4*)&cosT[l * 32 + (d & 31)];
        const float4 sn = *(const float4*)&sinT[l * 32 + (d & 31)];
        float e0 = v0 * cs.x - v1 * sn.x;
        float o0 = v1 * cs.y + v0 * sn.y;
        float e1 = v2 * cs.z - v3 * sn.z;
        float o1 = v3 * cs.w + v2 * sn.w;
        short* dst;
        if (three == 0) {
          const float S = 0.18033688011f;  // 1/sqrt(D) * log2(e)
          e0 *= S; o0 *= S; e1 *= S; o1 *= S;
          dst = qb;
        } else {
          dst = kbuf;
        }
        uint2 o = {pack2_bf16(e0, o0), pack2_bf16(e1, o1)};
        *(uint2*)&dst[doff] = o;
      }
    }
  }
}

// ---------------- V transpose: (B,H,L,D) -> (B,H,D,L) ----------------
__global__ __launch_bounds__(256) void transpose_v(const short* __restrict__ vbuf,
                                                   short* __restrict__ vTb) {
  __shared__ short T[64 * 72];
  const int bh = blockIdx.y;
  const int l0 = blockIdx.x * 64;
  const int t = threadIdx.x;
  const int row = t >> 3;
  const int cc = (t & 7) * 8;
  const short* src = vbuf + ((long)bh * 1024 + l0) * 64;
  for (int p = 0; p < 2; p++) {
    int lr = row + p * 32;
    *(bf16x8*)&T[lr * 72 + cc] = *(const bf16x8*)&src[(long)lr * 64 + cc];
  }
  __syncthreads();
  short* dst = vTb + (long)bh * 64 * 1024 + l0;
  for (int p = 0; p < 2; p++) {
    int d = row + p * 32;
    bf16x8 v;
    for (int j = 0; j < 8; j++) v[j] = T[(cc + j) * 72 + d];
    *(bf16x8*)&dst[(long)d * 1024 + cc] = v;
  }
}

// ---------------- flash attention v8 (v7 + XCD block swizzle) ----------------
__global__ __launch_bounds__(256, 5) void flash_attn(
    const short* __restrict__ qb, const short* __restrict__ kbuf,
    const short* __restrict__ vTb, const u64* __restrict__ maskb,
    short* __restrict__ attno) {
  __shared__ short K0[64 * 64], K1[64 * 64];
  __shared__ short V0[64 * 64], V1[64 * 64];
  const int t = threadIdx.x;
  const int wid = t >> 6, lane = t & 63;
  const int g = lane >> 4, c = lane & 15;
  // XCD swizzle: nwg=2048 (16x128); XCD k owns 256 contiguous tiles = 16 full (b,h)
  // K/V panels (4MB) -> L2-resident.
  const int bid = blockIdx.y * 16 + blockIdx.x;
  const int swz = (bid & 7) * 256 + (bid >> 3);
  const int q0 = (swz & 15) * 64;
  const int bh = swz >> 4;
  const int b = bh >> 4;
  const int h = bh & 15;
  const long qoff = (long)bh * 1024 * 64;
  const int qrow = q0 + wid * 16 + c;  // this lane's q column

  // Q fragment (B-operand of S^T mfma)
  bf16x8 aq0, aq1;
  {
    const short* qp = qb + qoff + (long)qrow * 64;
    aq0 = *(const bf16x8*)(qp + g * 8);
    aq1 = *(const bf16x8*)(qp + 32 + g * 8);
  }

  f32x4 Od[4];
  for (int i = 0; i < 4; i++) Od[i] = (f32x4){0.f, 0.f, 0.f, 0.f};
  f32x4 Ld = (f32x4){0.f, 0.f, 0.f, 0.f};  // row-sum acc: D[0][q] = sum_k P[k][q]
  float m_run = -1e30f;

  // ones-row A-operand (K=32): lanes with m-index 0 hold bf16 1.0 across k
  bf16x8 avOnes8;
  {
    union { bf16x8 v; u32 u[4]; } av;
    u32 o1 = (c == 0) ? 0x3F803F80u : 0u;
    av.u[0] = av.u[1] = av.u[2] = av.u[3] = o1;
    avOnes8 = av.v;
  }

  const u64* mrow = maskb + ((long)b * 1024 + qrow) * 16;
  const short* Kg = kbuf + qoff;
  const short* Vg = vTb + qoff;

  const int l8 = lane >> 3, l7 = lane & 7;
  const int sr = wid * 16 + l8;
  const int sch = ((l7 ^ l8) & 7) * 8;
  // K row permutation: LDS row r holds physical key phys(r) so that the z-reg
  // of (nt, g, reg) is physical key (nt>>1)*32 + g*8 + (nt&1)*4 + reg.
  const int r1 = wid * 16 + l8;
  const int r2 = r1 + 8;
  const int kp1 = (r1 & 32) | (((r1 & 15) >> 2) << 3) | (((r1 >> 4) & 1) << 2) | (r1 & 3);
  const int kp2 = (r2 & 32) | (((r2 & 15) >> 2) << 3) | (((r2 >> 4) & 1) << 2) | (r2 & 3);

  const int ck0 = g ^ (c & 7);
  const int kOff0 = c * 64 + ck0 * 8;
  const int kOff1 = c * 64 + (ck0 ^ 4) * 8;
  int vOff32[2];
  for (int kg = 0; kg < 2; kg++)
    vOff32[kg] = c * 64 + (((kg * 4 + g) ^ (c & 7)) * 8);

#define STAGE(KD, VD, ktn) do { \
    GLD_LDS16(Kg + (long)((ktn) + kp1) * 64 + sch,      &KD[(wid * 16) * 64]); \
    GLD_LDS16(Kg + (long)((ktn) + kp2) * 64 + sch,      &KD[(wid * 16 + 8) * 64]); \
    GLD_LDS16(Vg + (long)sr * 1024 + (ktn) + sch,       &VD[(wid * 16) * 64]); \
    GLD_LDS16(Vg + (long)(sr + 8) * 1024 + (ktn) + sch, &VD[(wid * 16 + 8) * 64]); \
  } while (0)

#define TILE(KB, VB, KP, VP, ki) do { \
    u64 mw = mrow[ki]; /* L3-resident, issued before the barrier */ \
    __syncthreads(); /* drains prefetch issued a full tile of compute ago */ \
    STAGE(KP, VP, (((ki) + 1) & 15) * 64); \
    f32x4 z[4]; \
    for (int nt = 0; nt < 4; nt++) { \
      bf16x8 bk0 = *(const bf16x8*)&KB[kOff0 + nt * 1024]; \
      bf16x8 bk1 = *(const bf16x8*)&KB[kOff1 + nt * 1024]; \
      f32x4 zz = (f32x4){0.f, 0.f, 0.f, 0.f}; \
      zz = __builtin_amdgcn_mfma_f32_16x16x32_bf16(bk0, aq0, zz, 0, 0, 0); \
      zz = __builtin_amdgcn_mfma_f32_16x16x32_bf16(bk1, aq1, zz, 0, 0, 0); \
      z[nt] = zz; \
    } \
    float mx = fmaxf(fmaxf(fmaxf(z[0][0], z[0][1]), fmaxf(z[0][2], z[0][3])), \
                     fmaxf(fmaxf(z[1][0], z[1][1]), fmaxf(z[1][2], z[1][3]))); \
    mx = fmaxf(mx, fmaxf(fmaxf(fmaxf(z[2][0], z[2][1]), fmaxf(z[2][2], z[2][3])), \
                         fmaxf(fmaxf(z[3][0], z[3][1]), fmaxf(z[3][2], z[3][3])))); \
    if (__ballot(mx > m_run + 8.f)) { /* rare after warm-up (T13) */ \
      mx = fmaxf(mx, __shfl_xor(mx, 16, 64)); \
      mx = fmaxf(mx, __shfl_xor(mx, 32, 64)); \
      float mnew = fmaxf(m_run, mx); \
      float al = exp2_fast(m_run - mnew); \
      for (int dt = 0; dt < 4; dt++) { \
        Od[dt][0] *= al; Od[dt][1] *= al; Od[dt][2] *= al; Od[dt][3] *= al; \
      } \
      Ld[0] *= al; \
      m_run = mnew; \
    } \
    for (int kg = 0; kg < 2; kg++) { \
      union { bf16x8 v; u32 u[4]; } pu; \
      for (int ntp = 0; ntp < 2; ntp++) { \
        const int nt = kg * 2 + ntp; \
        u32 m4 = (u32)(mw >> (kg * 32 + g * 8 + ntp * 4)) & 0xFu; \
        u32 mlo = ((m4 & 1u) ? 0xFFFFu : 0u) | ((m4 & 2u) ? 0xFFFF0000u : 0u); \
        u32 mhi = ((m4 & 4u) ? 0xFFFFu : 0u) | ((m4 & 8u) ? 0xFFFF0000u : 0u); \
        float p0 = exp2_fast(z[nt][0] - m_run); \
        float p1 = exp2_fast(z[nt][1] - m_run); \
        float p2 = exp2_fast(z[nt][2] - m_run); \
        float p3 = exp2_fast(z[nt][3] - m_run); \
        pu.u[ntp * 2 + 0] = pack2_bf16(p0, p1) & mlo; \
        pu.u[ntp * 2 + 1] = pack2_bf16(p2, p3) & mhi; \
      } \
      Ld = __builtin_amdgcn_mfma_f32_16x16x32_bf16(avOnes8, pu.v, Ld, 0, 0, 0); \
      for (int dt = 0; dt < 4; dt++) { \
        bf16x8 av = *(const bf16x8*)&VB[vOff32[kg] + dt * 1024]; \
        Od[dt] = __builtin_amdgcn_mfma_f32_16x16x32_bf16(av, pu.v, Od[dt], 0, 0, 0); \
      } \
    } \
  } while (0)

  STAGE(K0, V0, 0);
  for (int ki = 0; ki < 16; ki += 2) {
    TILE(K0, V0, K1, V1, ki);
    TILE(K1, V1, K0, V0, ki + 1);
  }
#undef TILE
#undef STAGE

  float lsum = __shfl(Ld[0], c, 64);
  float inv = 1.f / lsum;
  long rbase = ((long)qrow * 8 + b) * 1024 + h * 64 + g * 4;
  for (int dt = 0; dt < 4; dt++) {
    union { bf16x4 v; u32 u[2]; } o;
    o.u[0] = pack2_bf16(Od[dt][0] * inv, Od[dt][1] * inv);
    o.u[1] = pack2_bf16(Od[dt][2] * inv, Od[dt][3] * inv);
    *(bf16x4*)&attno[rbase + dt * 16] = o.v;
  }
}

// ---------------- GEMM 2: out = attno * Wo^T + bo (f32 out) ----------------
// v3: same single-barrier K-step + XCD swizzle (nwg=512, 64 tiles/XCD).
__global__ __launch_bounds__(256, 4) void gemm_out(
    const short* __restrict__ Ab, const short* __restrict__ Wob,
    const float* __restrict__ bo, float* __restrict__ out) {
  __shared__ short Ash[2][128 * 32];
  __shared__ short Bsh[2][128 * 32];
  const int tid = threadIdx.x;
  const int wid = tid >> 6, lane = tid & 63;
  const int g = lane >> 4, c = lane & 15;
  const int wm = wid >> 1, wn = wid & 1;
  const int bid = blockIdx.y * 8 + blockIdx.x;
  const int swz = (bid & 7) * 64 + (bid >> 3);
  const int m0 = (swz >> 3) * 128, n0 = (swz & 7) * 128;

  f32x4 acc[4][4];
  for (int i = 0; i < 4; i++)
    for (int j = 0; j < 4; j++) acc[i][j] = (f32x4){0.f, 0.f, 0.f, 0.f};

  const int srow = lane >> 2;
  const int scol = ((lane & 3) ^ ((lane >> 3) & 3)) * 8;
  const short* AgL = Ab + (long)(m0 + wid * 32 + srow) * 1024 + scol;
  const short* BgL = Wob + (long)(n0 + wid * 32 + srow) * 1024 + scol;
  const int dst0 = (wid * 32) * 32;
  const int dst1 = (wid * 32 + 16) * 32;
  const int ck = g ^ ((c >> 1) & 3);

#define OUT_STAGE(PA, PB, nko) do { \
    GLD_LDS16(AgL + (nko), &(PA)[dst0]); \
    GLD_LDS16(AgL + (nko) + 16 * 1024, &(PA)[dst1]); \
    GLD_LDS16(BgL + (nko), &(PB)[dst0]); \
    GLD_LDS16(BgL + (nko) + 16 * 1024, &(PB)[dst1]); \
  } while (0)

#define OUT_COMPUTE(CA, CB) do { \
    bf16x8 af[4], bfr[4]; \
    for (int i = 0; i < 4; i++) \
      af[i] = *(const bf16x8*)&(CA)[(wm * 64 + i * 16 + c) * 32 + ck * 8]; \
    for (int j = 0; j < 4; j++) \
      bfr[j] = *(const bf16x8*)&(CB)[(wn * 64 + j * 16 + c) * 32 + ck * 8]; \
    for (int i = 0; i < 4; i++) \
      for (int j = 0; j < 4; j++) \
        acc[i][j] = __builtin_amdgcn_mfma_f32_16x16x32_bf16(af[i], bfr[j], acc[i][j], 0, 0, 0); \
  } while (0)

  OUT_STAGE(Ash[0], Bsh[0], 0);
  __syncthreads();
  for (int kt = 0; kt < 32; kt += 2) {
    OUT_STAGE(Ash[1], Bsh[1], (kt + 1) * 32);
    OUT_COMPUTE(Ash[0], Bsh[0]);
    __syncthreads();
    if (kt + 2 < 32) OUT_STAGE(Ash[0], Bsh[0], (kt + 2) * 32);
    OUT_COMPUTE(Ash[1], Bsh[1]);
    __syncthreads();
  }
#undef OUT_STAGE
#undef OUT_COMPUTE

  for (int jt = 0; jt < 4; jt++) {
    const int j = n0 + wn * 64 + jt * 16 + c;
    const float bias = bo[j];
    for (int i = 0; i < 4; i++) {
      const int rbase = m0 + wm * 64 + i * 16 + g * 4;
      for (int reg = 0; reg < 4; reg++)
        out[(long)(rbase + reg) * 1024 + j] = acc[i][jt][reg] + bias;
    }
  }
}

// ---------------- launcher ----------------
extern "C" void kernel_launch(void* const* d_in, const int* in_sizes, int n_in,
                              void* d_out, int out_size, void* d_ws, size_t ws_size,
                              hipStream_t stream) {
  const float* hs = (const float*)d_in[0];
  const float* rpe = (const float*)d_in[1];
  const int* amask = (const int*)d_in[2];
  const float* Wqkv = (const float*)d_in[3];
  const float* bqkv = (const float*)d_in[4];
  const float* Wo = (const float*)d_in[5];
  const float* bo = (const float*)d_in[6];
  float* out = (float*)d_out;

  char* ws = (char*)d_ws;
  auto alloc = [&](size_t bytes) {
    char* p = ws;
    ws += (bytes + 255) & ~(size_t)255;
    return p;
  };
  short* Xb = (short*)alloc(8192LL * 1024 * 2);
  short* Wqkvb = (short*)alloc(3072LL * 1024 * 2);
  short* Wob = (short*)alloc(1024LL * 1024 * 2);
  float* cosT = (float*)alloc(1024 * 32 * 4);
  float* sinT = (float*)alloc(1024 * 32 * 4);
  u64* maskb = (u64*)alloc(8LL * 1024 * 16 * 8);
  short* qb = (short*)alloc(128LL * 1024 * 64 * 2);
  short* kbuf = (short*)alloc(128LL * 1024 * 64 * 2);
  short* vbuf = (short*)alloc(128LL * 1024 * 64 * 2);
  short* vTb = (short*)alloc(128LL * 1024 * 64 * 2);
  short* attno = (short*)alloc(8192LL * 1024 * 2);

  prep_all<<<45184, 256, 0, stream>>>(amask, maskb, hs, Wqkv, Wo, Xb, Wqkvb, Wob,
                                      rpe, cosT, sinT);
  gemm_qkv<<<dim3(24, 64), 256, 0, stream>>>(Xb, Wqkvb, bqkv, cosT, sinT, qb, kbuf, vbuf);
  transpose_v<<<dim3(16, 128), 256, 0, stream>>>(vbuf, vTb);
  flash_attn<<<dim3(16, 128), 256, 0, stream>>>(qb, kbuf, vTb, maskb, attno);
  gemm_out<<<dim3(8, 64), 256, 0, stream>>>(attno, Wob, bo, out);
}

// Round 4
// 311.355 us; speedup vs baseline: 1.1091x; 1.0095x over previous
//
#include <hip/hip_runtime.h>
#include <hip/hip_bf16.h>

typedef short bf16x8 __attribute__((ext_vector_type(8)));
typedef short bf16x4 __attribute__((ext_vector_type(4)));
typedef float f32x4 __attribute__((ext_vector_type(4)));
typedef unsigned int u32;
typedef unsigned long long u64;

#define GLD_LDS16(gp, lp) \
  __builtin_amdgcn_global_load_lds((const __attribute__((address_space(1))) u32*)(gp), \
                                   (__attribute__((address_space(3))) u32*)(lp), 16, 0, 0)

__device__ __forceinline__ short f2bf(float f) {
  u32 u = __builtin_bit_cast(u32, f);
  u = (u + 0x7fffu + ((u >> 16) & 1u)) >> 16;
  return (short)u;
}

// gfx950 has no cvt_pk_bf16 builtin (m240) -- hardware op via inline asm.
__device__ __forceinline__ u32 pack2_bf16(float a, float b) {
#if __has_builtin(__builtin_amdgcn_cvt_pk_bf16_f32)
  typedef __bf16 bf16v2 __attribute__((ext_vector_type(2)));
  bf16v2 r = __builtin_amdgcn_cvt_pk_bf16_f32(a, b);
  return __builtin_bit_cast(u32, r);
#else
  u32 r;
  asm("v_cvt_pk_bf16_f32 %0, %1, %2" : "=v"(r) : "v"(a), "v"(b));
  return r;
#endif
}

__device__ __forceinline__ float exp2_fast(float x) {
#if __has_builtin(__builtin_amdgcn_exp2f)
  return __builtin_amdgcn_exp2f(x);
#else
  return exp2f(x);
#endif
}

// ---------------- fused prep: mask_pack (32768 blk) + cvt (12288 blk) + rope (128 blk) ----
__global__ __launch_bounds__(256) void prep_all(
    const int* __restrict__ m, u64* __restrict__ maskb,
    const float* __restrict__ hs, const float* __restrict__ wqkv,
    const float* __restrict__ wo, short* __restrict__ xb,
    short* __restrict__ wqkvb, short* __restrict__ wob,
    const float* __restrict__ rpe, float* __restrict__ cosT,
    float* __restrict__ sinT) {
  int b = blockIdx.x;
  if (b < 32768) {
    int i = b * 256 + threadIdx.x;
    u64 bm = __ballot(m[i] != 0);
    if ((threadIdx.x & 63) == 0) maskb[i >> 6] = bm;
    return;
  }
  b -= 32768;
  if (b < 12288) {
    const float* in;
    short* out;
    int base;
    if (b < 8192) {
      in = hs; out = xb; base = b * 1024;
    } else if (b < 8192 + 3072) {
      in = wqkv; out = wqkvb; base = (b - 8192) * 1024;
    } else {
      in = wo; out = wob; base = (b - 11264) * 1024;
    }
    int i = base + threadIdx.x * 4;
    float4 v = *(const float4*)(in + i);
    short4 o;
    o.x = f2bf(v.x); o.y = f2bf(v.y); o.z = f2bf(v.z); o.w = f2bf(v.w);
    *(short4*)(out + i) = o;
    return;
  }
  b -= 12288;
  int i = b * 256 + threadIdx.x;  // 32768 = 1024*32
  float v = rpe[i];
  cosT[i] = cosf(v);
  sinT[i] = sinf(v);
}

// ---------------- GEMM 1 v4: deep-pipelined (T3+T4+T2+T5) ----------------
// Tile 128x256, BK=64, 512 thr = 8 waves (2M x 4N), per-wave 64x64 out.
// 3-buffer LDS rotation (3 x 48KB); iteration kt stages K-tile kt+2 (6 x 8KB
// pieces, 3 per phase) -> every piece has a 2-4 phase lead. vmcnt(6) checkpoint
// ONCE per K-tile (never 0 until kt=14 drain): exactly the next K-tile's loads
// must land, the following tile's 6 stay in flight across barriers.
// Per phase: {8 ds_read_b128 || 3 global_load_lds -> bar -> lgkmcnt(0) ->
// setprio(1) 16 MFMA setprio(0) -> bar}. XOR chunk swizzle (conflicts=0, r2).
// Operands swapped (mfma(b,a)): D row=channel, col=token -> in-reg RoPE.
__global__ __launch_bounds__(512, 2) void gemm_qkv(
    const short* __restrict__ Xb, const short* __restrict__ Wb,
    const float* __restrict__ bqkv, const float* __restrict__ cosT,
    const float* __restrict__ sinT, short* __restrict__ qb,
    short* __restrict__ kbuf, short* __restrict__ vbuf) {
  __shared__ short lds[3][24576];  // [buf][A:128x64 | B:256x64]
  const int tid = threadIdx.x;
  const int wid = tid >> 6, lane = tid & 63;
  const int g = lane >> 4, c = lane & 15;
  const int wm = wid >> 2, wn = wid & 3;
  // XCD swizzle: nwg=768 (12 x 64), 96 contiguous tiles per XCD
  const int bid = blockIdx.y * 12 + blockIdx.x;
  const int swz = (bid & 7) * 96 + (bid >> 3);
  const int m0 = (swz / 12) * 128, n0 = (swz % 12) * 256;

  f32x4 acc[4][4];
#pragma unroll
  for (int i = 0; i < 4; i++)
#pragma unroll
    for (int j = 0; j < 4; j++) acc[i][j] = (f32x4){0.f, 0.f, 0.f, 0.f};

  // staging: thread t covers row t>>3 of a 64-row piece, physical 16B slot t&7;
  // global chunk pre-swizzled by (row&7) so LDS dest stays linear (rule #21).
  const int trow = tid >> 3;
  const int gch = ((tid & 7) ^ (trow & 7)) * 8;
  const short* Ag = Xb + (long)(m0 + trow) * 1024 + gch;
  const short* Bg = Wb + (long)(n0 + trow) * 1024 + gch;
  const int lo = tid * 8;  // shorts: (t>>3)*64 + (t&7)*8

  // fragment bases (shorts): row = (wseg*64 + f*16 + c), chunk = (kh*4+g)^(c&7)
  const int fA = (wm * 64 + c) * 64;
  const int fB = 8192 + (wn * 64 + c) * 64;
  const int ck0 = (g ^ (c & 7)) * 8;  // kh=1: ck0 ^ 32

#define QKV_STG_P0(bs, ko) do { \
    GLD_LDS16(Ag + (ko),             &lds[bs][lo]); \
    GLD_LDS16(Ag + (ko) + 64 * 1024, &lds[bs][4096 + lo]); \
    GLD_LDS16(Bg + (ko),             &lds[bs][8192 + lo]); \
  } while (0)
#define QKV_STG_P1(bs, ko) do { \
    GLD_LDS16(Bg + (ko) + 64 * 1024,  &lds[bs][12288 + lo]); \
    GLD_LDS16(Bg + (ko) + 128 * 1024, &lds[bs][16384 + lo]); \
    GLD_LDS16(Bg + (ko) + 192 * 1024, &lds[bs][20480 + lo]); \
  } while (0)

  // prologue: stage kt0+kt1 fully; wait kt0 (6 newest stay in flight)
  QKV_STG_P0(0, 0);  QKV_STG_P1(0, 0);
  QKV_STG_P0(1, 64); QKV_STG_P1(1, 64);
  asm volatile("s_waitcnt vmcnt(6)" ::: "memory");
  __builtin_amdgcn_s_barrier();

  int bc = 0;
  for (int kt = 0; kt < 16; ++kt) {
    const short* Bf = &lds[bc][0];
    const int bs = (bc + 2 >= 3) ? bc - 1 : bc + 2;  // (bc+2)%3
    const int ko2 = (kt + 2) * 64;
    bf16x8 af[4], bfr[4];

    // ---- phase 0 (K-half 0) ----
#pragma unroll
    for (int mf = 0; mf < 4; mf++) af[mf] = *(const bf16x8*)&Bf[fA + mf * 1024 + ck0];
#pragma unroll
    for (int nf = 0; nf < 4; nf++) bfr[nf] = *(const bf16x8*)&Bf[fB + nf * 1024 + ck0];
    if (kt < 14) QKV_STG_P0(bs, ko2);
    __builtin_amdgcn_s_barrier();
    asm volatile("s_waitcnt lgkmcnt(0)" ::: "memory");
    __builtin_amdgcn_sched_barrier(0);
    __builtin_amdgcn_s_setprio(1);
#pragma unroll
    for (int mf = 0; mf < 4; mf++)
#pragma unroll
      for (int nf = 0; nf < 4; nf++)
        acc[mf][nf] = __builtin_amdgcn_mfma_f32_16x16x32_bf16(bfr[nf], af[mf], acc[mf][nf], 0, 0, 0);
    __builtin_amdgcn_s_setprio(0);
    __builtin_amdgcn_s_barrier();

    // ---- phase 1 (K-half 1) ----
#pragma unroll
    for (int mf = 0; mf < 4; mf++) af[mf] = *(const bf16x8*)&Bf[fA + mf * 1024 + (ck0 ^ 32)];
#pragma unroll
    for (int nf = 0; nf < 4; nf++) bfr[nf] = *(const bf16x8*)&Bf[fB + nf * 1024 + (ck0 ^ 32)];
    if (kt < 14) QKV_STG_P1(bs, ko2);
    __builtin_amdgcn_s_barrier();
    asm volatile("s_waitcnt lgkmcnt(0)" ::: "memory");
    __builtin_amdgcn_sched_barrier(0);
    __builtin_amdgcn_s_setprio(1);
#pragma unroll
    for (int mf = 0; mf < 4; mf++)
#pragma unroll
      for (int nf = 0; nf < 4; nf++)
        acc[mf][nf] = __builtin_amdgcn_mfma_f32_16x16x32_bf16(bfr[nf], af[mf], acc[mf][nf], 0, 0, 0);
    __builtin_amdgcn_s_setprio(0);
    // checkpoint: next K-tile's 6 loads must have landed; tile-after's 6 stay in flight
    if (kt < 14) {
      asm volatile("s_waitcnt vmcnt(6)" ::: "memory");
    } else if (kt == 14) {
      asm volatile("s_waitcnt vmcnt(0)" ::: "memory");
    }
    __builtin_amdgcn_s_barrier();
    bc = (bc + 1 == 3) ? 0 : bc + 1;
  }
#undef QKV_STG_P0
#undef QKV_STG_P1

  // epilogue: lane owns token r (col=c), 4 consecutive channels (rows=g*4+reg)
  for (int jt = 0; jt < 4; jt++) {
    const int chan = n0 + wn * 64 + jt * 16 + g * 4;  // %4 == 0
    const int three = chan >> 10;
    const int hh = (chan >> 6) & 15;
    const int d = chan & 63;
    const float4 bq = *(const float4*)&bqkv[chan];
    for (int i = 0; i < 4; i++) {
      const int r = m0 + wm * 64 + i * 16 + c;
      const int l = r >> 3, b = r & 7;
      float v0 = acc[i][jt][0] + bq.x;
      float v1 = acc[i][jt][1] + bq.y;
      float v2 = acc[i][jt][2] + bq.z;
      float v3 = acc[i][jt][3] + bq.w;
      const long doff = ((long)(b * 16 + hh) * 1024 + l) * 64 + d;
      if (three == 2) {
        uint2 o = {pack2_bf16(v0, v1), pack2_bf16(v2, v3)};
        *(uint2*)&vbuf[doff] = o;
      } else {
        const float4 cs = *(const float4*)&cosT[l * 32 + (d & 31)];
        const float4 sn = *(const float4*)&sinT[l * 32 + (d & 31)];
        float e0 = v0 * cs.x - v1 * sn.x;
        float o0 = v1 * cs.y + v0 * sn.y;
        float e1 = v2 * cs.z - v3 * sn.z;
        float o1 = v3 * cs.w + v2 * sn.w;
        short* dst;
        if (three == 0) {
          const float S = 0.18033688011f;  // 1/sqrt(D) * log2(e)
          e0 *= S; o0 *= S; e1 *= S; o1 *= S;
          dst = qb;
        } else {
          dst = kbuf;
        }
        uint2 o = {pack2_bf16(e0, o0), pack2_bf16(e1, o1)};
        *(uint2*)&dst[doff] = o;
      }
    }
  }
}

// ---------------- V transpose: (B,H,L,D) -> (B,H,D,L) ----------------
__global__ __launch_bounds__(256) void transpose_v(const short* __restrict__ vbuf,
                                                   short* __restrict__ vTb) {
  __shared__ short T[64 * 72];
  const int bh = blockIdx.y;
  const int l0 = blockIdx.x * 64;
  const int t = threadIdx.x;
  const int row = t >> 3;
  const int cc = (t & 7) * 8;
  const short* src = vbuf + ((long)bh * 1024 + l0) * 64;
  for (int p = 0; p < 2; p++) {
    int lr = row + p * 32;
    *(bf16x8*)&T[lr * 72 + cc] = *(const bf16x8*)&src[(long)lr * 64 + cc];
  }
  __syncthreads();
  short* dst = vTb + (long)bh * 64 * 1024 + l0;
  for (int p = 0; p < 2; p++) {
    int d = row + p * 32;
    bf16x8 v;
    for (int j = 0; j < 8; j++) v[j] = T[(cc + j) * 72 + d];
    *(bf16x8*)&dst[(long)d * 1024 + cc] = v;
  }
}

// ---------------- flash attention v8 (unchanged) ----------------
__global__ __launch_bounds__(256, 5) void flash_attn(
    const short* __restrict__ qb, const short* __restrict__ kbuf,
    const short* __restrict__ vTb, const u64* __restrict__ maskb,
    short* __restrict__ attno) {
  __shared__ short K0[64 * 64], K1[64 * 64];
  __shared__ short V0[64 * 64], V1[64 * 64];
  const int t = threadIdx.x;
  const int wid = t >> 6, lane = t & 63;
  const int g = lane >> 4, c = lane & 15;
  const int bid = blockIdx.y * 16 + blockIdx.x;
  const int swz = (bid & 7) * 256 + (bid >> 3);
  const int q0 = (swz & 15) * 64;
  const int bh = swz >> 4;
  const int b = bh >> 4;
  const int h = bh & 15;
  const long qoff = (long)bh * 1024 * 64;
  const int qrow = q0 + wid * 16 + c;

  bf16x8 aq0, aq1;
  {
    const short* qp = qb + qoff + (long)qrow * 64;
    aq0 = *(const bf16x8*)(qp + g * 8);
    aq1 = *(const bf16x8*)(qp + 32 + g * 8);
  }

  f32x4 Od[4];
  for (int i = 0; i < 4; i++) Od[i] = (f32x4){0.f, 0.f, 0.f, 0.f};
  f32x4 Ld = (f32x4){0.f, 0.f, 0.f, 0.f};
  float m_run = -1e30f;

  bf16x8 avOnes8;
  {
    union { bf16x8 v; u32 u[4]; } av;
    u32 o1 = (c == 0) ? 0x3F803F80u : 0u;
    av.u[0] = av.u[1] = av.u[2] = av.u[3] = o1;
    avOnes8 = av.v;
  }

  const u64* mrow = maskb + ((long)b * 1024 + qrow) * 16;
  const short* Kg = kbuf + qoff;
  const short* Vg = vTb + qoff;

  const int l8 = lane >> 3, l7 = lane & 7;
  const int sr = wid * 16 + l8;
  const int sch = ((l7 ^ l8) & 7) * 8;
  const int r1 = wid * 16 + l8;
  const int r2 = r1 + 8;
  const int kp1 = (r1 & 32) | (((r1 & 15) >> 2) << 3) | (((r1 >> 4) & 1) << 2) | (r1 & 3);
  const int kp2 = (r2 & 32) | (((r2 & 15) >> 2) << 3) | (((r2 >> 4) & 1) << 2) | (r2 & 3);

  const int ck0 = g ^ (c & 7);
  const int kOff0 = c * 64 + ck0 * 8;
  const int kOff1 = c * 64 + (ck0 ^ 4) * 8;
  int vOff32[2];
  for (int kg = 0; kg < 2; kg++)
    vOff32[kg] = c * 64 + (((kg * 4 + g) ^ (c & 7)) * 8);

#define STAGE(KD, VD, ktn) do { \
    GLD_LDS16(Kg + (long)((ktn) + kp1) * 64 + sch,      &KD[(wid * 16) * 64]); \
    GLD_LDS16(Kg + (long)((ktn) + kp2) * 64 + sch,      &KD[(wid * 16 + 8) * 64]); \
    GLD_LDS16(Vg + (long)sr * 1024 + (ktn) + sch,       &VD[(wid * 16) * 64]); \
    GLD_LDS16(Vg + (long)(sr + 8) * 1024 + (ktn) + sch, &VD[(wid * 16 + 8) * 64]); \
  } while (0)

#define TILE(KB, VB, KP, VP, ki) do { \
    u64 mw = mrow[ki]; \
    __syncthreads(); \
    STAGE(KP, VP, (((ki) + 1) & 15) * 64); \
    f32x4 z[4]; \
    for (int nt = 0; nt < 4; nt++) { \
      bf16x8 bk0 = *(const bf16x8*)&KB[kOff0 + nt * 1024]; \
      bf16x8 bk1 = *(const bf16x8*)&KB[kOff1 + nt * 1024]; \
      f32x4 zz = (f32x4){0.f, 0.f, 0.f, 0.f}; \
      zz = __builtin_amdgcn_mfma_f32_16x16x32_bf16(bk0, aq0, zz, 0, 0, 0); \
      zz = __builtin_amdgcn_mfma_f32_16x16x32_bf16(bk1, aq1, zz, 0, 0, 0); \
      z[nt] = zz; \
    } \
    float mx = fmaxf(fmaxf(fmaxf(z[0][0], z[0][1]), fmaxf(z[0][2], z[0][3])), \
                     fmaxf(fmaxf(z[1][0], z[1][1]), fmaxf(z[1][2], z[1][3]))); \
    mx = fmaxf(mx, fmaxf(fmaxf(fmaxf(z[2][0], z[2][1]), fmaxf(z[2][2], z[2][3])), \
                         fmaxf(fmaxf(z[3][0], z[3][1]), fmaxf(z[3][2], z[3][3])))); \
    if (__ballot(mx > m_run + 8.f)) { \
      mx = fmaxf(mx, __shfl_xor(mx, 16, 64)); \
      mx = fmaxf(mx, __shfl_xor(mx, 32, 64)); \
      float mnew = fmaxf(m_run, mx); \
      float al = exp2_fast(m_run - mnew); \
      for (int dt = 0; dt < 4; dt++) { \
        Od[dt][0] *= al; Od[dt][1] *= al; Od[dt][2] *= al; Od[dt][3] *= al; \
      } \
      Ld[0] *= al; \
      m_run = mnew; \
    } \
    for (int kg = 0; kg < 2; kg++) { \
      union { bf16x8 v; u32 u[4]; } pu; \
      for (int ntp = 0; ntp < 2; ntp++) { \
        const int nt = kg * 2 + ntp; \
        u32 m4 = (u32)(mw >> (kg * 32 + g * 8 + ntp * 4)) & 0xFu; \
        u32 mlo = ((m4 & 1u) ? 0xFFFFu : 0u) | ((m4 & 2u) ? 0xFFFF0000u : 0u); \
        u32 mhi = ((m4 & 4u) ? 0xFFFFu : 0u) | ((m4 & 8u) ? 0xFFFF0000u : 0u); \
        float p0 = exp2_fast(z[nt][0] - m_run); \
        float p1 = exp2_fast(z[nt][1] - m_run); \
        float p2 = exp2_fast(z[nt][2] - m_run); \
        float p3 = exp2_fast(z[nt][3] - m_run); \
        pu.u[ntp * 2 + 0] = pack2_bf16(p0, p1) & mlo; \
        pu.u[ntp * 2 + 1] = pack2_bf16(p2, p3) & mhi; \
      } \
      Ld = __builtin_amdgcn_mfma_f32_16x16x32_bf16(avOnes8, pu.v, Ld, 0, 0, 0); \
      for (int dt = 0; dt < 4; dt++) { \
        bf16x8 av = *(const bf16x8*)&VB[vOff32[kg] + dt * 1024]; \
        Od[dt] = __builtin_amdgcn_mfma_f32_16x16x32_bf16(av, pu.v, Od[dt], 0, 0, 0); \
      } \
    } \
  } while (0)

  STAGE(K0, V0, 0);
  for (int ki = 0; ki < 16; ki += 2) {
    TILE(K0, V0, K1, V1, ki);
    TILE(K1, V1, K0, V0, ki + 1);
  }
#undef TILE
#undef STAGE

  float lsum = __shfl(Ld[0], c, 64);
  float inv = 1.f / lsum;
  long rbase = ((long)qrow * 8 + b) * 1024 + h * 64 + g * 4;
  for (int dt = 0; dt < 4; dt++) {
    union { bf16x4 v; u32 u[2]; } o;
    o.u[0] = pack2_bf16(Od[dt][0] * inv, Od[dt][1] * inv);
    o.u[1] = pack2_bf16(Od[dt][2] * inv, Od[dt][3] * inv);
    *(bf16x4*)&attno[rbase + dt * 16] = o.v;
  }
}

// ---------------- GEMM 2: out = attno * Wo^T + bo (f32 out), v3 unchanged ----------------
__global__ __launch_bounds__(256, 4) void gemm_out(
    const short* __restrict__ Ab, const short* __restrict__ Wob,
    const float* __restrict__ bo, float* __restrict__ out) {
  __shared__ short Ash[2][128 * 32];
  __shared__ short Bsh[2][128 * 32];
  const int tid = threadIdx.x;
  const int wid = tid >> 6, lane = tid & 63;
  const int g = lane >> 4, c = lane & 15;
  const int wm = wid >> 1, wn = wid & 1;
  const int bid = blockIdx.y * 8 + blockIdx.x;
  const int swz = (bid & 7) * 64 + (bid >> 3);
  const int m0 = (swz >> 3) * 128, n0 = (swz & 7) * 128;

  f32x4 acc[4][4];
  for (int i = 0; i < 4; i++)
    for (int j = 0; j < 4; j++) acc[i][j] = (f32x4){0.f, 0.f, 0.f, 0.f};

  const int srow = lane >> 2;
  const int scol = ((lane & 3) ^ ((lane >> 3) & 3)) * 8;
  const short* AgL = Ab + (long)(m0 + wid * 32 + srow) * 1024 + scol;
  const short* BgL = Wob + (long)(n0 + wid * 32 + srow) * 1024 + scol;
  const int dst0 = (wid * 32) * 32;
  const int dst1 = (wid * 32 + 16) * 32;
  const int ck = g ^ ((c >> 1) & 3);

#define OUT_STAGE(PA, PB, nko) do { \
    GLD_LDS16(AgL + (nko), &(PA)[dst0]); \
    GLD_LDS16(AgL + (nko) + 16 * 1024, &(PA)[dst1]); \
    GLD_LDS16(BgL + (nko), &(PB)[dst0]); \
    GLD_LDS16(BgL + (nko) + 16 * 1024, &(PB)[dst1]); \
  } while (0)

#define OUT_COMPUTE(CA, CB) do { \
    bf16x8 af[4], bfr[4]; \
    for (int i = 0; i < 4; i++) \
      af[i] = *(const bf16x8*)&(CA)[(wm * 64 + i * 16 + c) * 32 + ck * 8]; \
    for (int j = 0; j < 4; j++) \
      bfr[j] = *(const bf16x8*)&(CB)[(wn * 64 + j * 16 + c) * 32 + ck * 8]; \
    for (int i = 0; i < 4; i++) \
      for (int j = 0; j < 4; j++) \
        acc[i][j] = __builtin_amdgcn_mfma_f32_16x16x32_bf16(af[i], bfr[j], acc[i][j], 0, 0, 0); \
  } while (0)

  OUT_STAGE(Ash[0], Bsh[0], 0);
  __syncthreads();
  for (int kt = 0; kt < 32; kt += 2) {
    OUT_STAGE(Ash[1], Bsh[1], (kt + 1) * 32);
    OUT_COMPUTE(Ash[0], Bsh[0]);
    __syncthreads();
    if (kt + 2 < 32) OUT_STAGE(Ash[0], Bsh[0], (kt + 2) * 32);
    OUT_COMPUTE(Ash[1], Bsh[1]);
    __syncthreads();
  }
#undef OUT_STAGE
#undef OUT_COMPUTE

  for (int jt = 0; jt < 4; jt++) {
    const int j = n0 + wn * 64 + jt * 16 + c;
    const float bias = bo[j];
    for (int i = 0; i < 4; i++) {
      const int rbase = m0 + wm * 64 + i * 16 + g * 4;
      for (int reg = 0; reg < 4; reg++)
        out[(long)(rbase + reg) * 1024 + j] = acc[i][jt][reg] + bias;
    }
  }
}

// ---------------- launcher ----------------
extern "C" void kernel_launch(void* const* d_in, const int* in_sizes, int n_in,
                              void* d_out, int out_size, void* d_ws, size_t ws_size,
                              hipStream_t stream) {
  const float* hs = (const float*)d_in[0];
  const float* rpe = (const float*)d_in[1];
  const int* amask = (const int*)d_in[2];
  const float* Wqkv = (const float*)d_in[3];
  const float* bqkv = (const float*)d_in[4];
  const float* Wo = (const float*)d_in[5];
  const float* bo = (const float*)d_in[6];
  float* out = (float*)d_out;

  char* ws = (char*)d_ws;
  auto alloc = [&](size_t bytes) {
    char* p = ws;
    ws += (bytes + 255) & ~(size_t)255;
    return p;
  };
  short* Xb = (short*)alloc(8192LL * 1024 * 2);
  short* Wqkvb = (short*)alloc(3072LL * 1024 * 2);
  short* Wob = (short*)alloc(1024LL * 1024 * 2);
  float* cosT = (float*)alloc(1024 * 32 * 4);
  float* sinT = (float*)alloc(1024 * 32 * 4);
  u64* maskb = (u64*)alloc(8LL * 1024 * 16 * 8);
  short* qb = (short*)alloc(128LL * 1024 * 64 * 2);
  short* kbuf = (short*)alloc(128LL * 1024 * 64 * 2);
  short* vbuf = (short*)alloc(128LL * 1024 * 64 * 2);
  short* vTb = (short*)alloc(128LL * 1024 * 64 * 2);
  short* attno = (short*)alloc(8192LL * 1024 * 2);

  prep_all<<<45184, 256, 0, stream>>>(amask, maskb, hs, Wqkv, Wo, Xb, Wqkvb, Wob,
                                      rpe, cosT, sinT);
  gemm_qkv<<<dim3(12, 64), 512, 0, stream>>>(Xb, Wqkvb, bqkv, cosT, sinT, qb, kbuf, vbuf);
  transpose_v<<<dim3(16, 128), 256, 0, stream>>>(vbuf, vTb);
  flash_attn<<<dim3(16, 128), 256, 0, stream>>>(qb, kbuf, vTb, maskb, attno);
  gemm_out<<<dim3(8, 64), 256, 0, stream>>>(attno, Wob, bo, out);
}

// Round 5
// 304.341 us; speedup vs baseline: 1.1346x; 1.0230x over previous
//
#include <hip/hip_runtime.h>
#include <hip/hip_bf16.h>

typedef short bf16x8 __attribute__((ext_vector_type(8)));
typedef short bf16x4 __attribute__((ext_vector_type(4)));
typedef float f32x4 __attribute__((ext_vector_type(4)));
typedef unsigned int u32;
typedef unsigned long long u64;

#define GLD_LDS16(gp, lp) \
  __builtin_amdgcn_global_load_lds((const __attribute__((address_space(1))) u32*)(gp), \
                                   (__attribute__((address_space(3))) u32*)(lp), 16, 0, 0)

__device__ __forceinline__ short f2bf(float f) {
  u32 u = __builtin_bit_cast(u32, f);
  u = (u + 0x7fffu + ((u >> 16) & 1u)) >> 16;
  return (short)u;
}

// gfx950 has no cvt_pk_bf16 builtin (m240) -- hardware op via inline asm.
__device__ __forceinline__ u32 pack2_bf16(float a, float b) {
#if __has_builtin(__builtin_amdgcn_cvt_pk_bf16_f32)
  typedef __bf16 bf16v2 __attribute__((ext_vector_type(2)));
  bf16v2 r = __builtin_amdgcn_cvt_pk_bf16_f32(a, b);
  return __builtin_bit_cast(u32, r);
#else
  u32 r;
  asm("v_cvt_pk_bf16_f32 %0, %1, %2" : "=v"(r) : "v"(a), "v"(b));
  return r;
#endif
}

__device__ __forceinline__ float exp2_fast(float x) {
#if __has_builtin(__builtin_amdgcn_exp2f)
  return __builtin_amdgcn_exp2f(x);
#else
  return exp2f(x);
#endif
}

// ---------------- fused prep: mask_pack (32768 blk) + cvt (12288 blk) + rope (128 blk) ----
__global__ __launch_bounds__(256) void prep_all(
    const int* __restrict__ m, u64* __restrict__ maskb,
    const float* __restrict__ hs, const float* __restrict__ wqkv,
    const float* __restrict__ wo, short* __restrict__ xb,
    short* __restrict__ wqkvb, short* __restrict__ wob,
    const float* __restrict__ rpe, float* __restrict__ cosT,
    float* __restrict__ sinT) {
  int b = blockIdx.x;
  if (b < 32768) {
    int i = b * 256 + threadIdx.x;
    u64 bm = __ballot(m[i] != 0);
    if ((threadIdx.x & 63) == 0) maskb[i >> 6] = bm;
    return;
  }
  b -= 32768;
  if (b < 12288) {
    const float* in;
    short* out;
    int base;
    if (b < 8192) {
      in = hs; out = xb; base = b * 1024;
    } else if (b < 8192 + 3072) {
      in = wqkv; out = wqkvb; base = (b - 8192) * 1024;
    } else {
      in = wo; out = wob; base = (b - 11264) * 1024;
    }
    int i = base + threadIdx.x * 4;
    float4 v = *(const float4*)(in + i);
    short4 o;
    o.x = f2bf(v.x); o.y = f2bf(v.y); o.z = f2bf(v.z); o.w = f2bf(v.w);
    *(short4*)(out + i) = o;
    return;
  }
  b -= 12288;
  int i = b * 256 + threadIdx.x;  // 32768 = 1024*32
  float v = rpe[i];
  cosT[i] = cosf(v);
  sinT[i] = sinf(v);
}

// ---------------- GEMM 1 v5: reg-dbuf pipeline, ONE barrier per K-tile ----------------
// Tile 128x256, BK=64, 512 thr = 8 waves (2M x 4N). 3-buffer LDS rotation.
// Fragment sets double-buffered in VGPRs: ds_reads for the next K=32 half are in
// flight WHILE the current half's 16 MFMAs run (compiler emits counted lgkmcnt
// before first use). Single vmcnt(0)+s_barrier per K-tile, sandwiched between the
// two MFMA half-clusters so the stage-wait hides under compute.
// Race guard: STG(kt+2) overwrites buf[kt-1]; all reads of buf[kt-1] are drained
// by each wave's iter-(kt-1) MFMA lgkm-wait, which precedes this barrier.
__global__ __launch_bounds__(512, 2) void gemm_qkv(
    const short* __restrict__ Xb, const short* __restrict__ Wb,
    const float* __restrict__ bqkv, const float* __restrict__ cosT,
    const float* __restrict__ sinT, short* __restrict__ qb,
    short* __restrict__ kbuf, short* __restrict__ vbuf) {
  __shared__ short lds[3][24576];  // [buf][A:128x64 | B:256x64]
  const int tid = threadIdx.x;
  const int wid = tid >> 6, lane = tid & 63;
  const int g = lane >> 4, c = lane & 15;
  const int wm = wid >> 2, wn = wid & 3;
  // XCD swizzle: nwg=768 (12 x 64), 96 contiguous tiles per XCD
  const int bid = blockIdx.y * 12 + blockIdx.x;
  const int swz = (bid & 7) * 96 + (bid >> 3);
  const int m0 = (swz / 12) * 128, n0 = (swz % 12) * 256;

  f32x4 acc[4][4];
#pragma unroll
  for (int i = 0; i < 4; i++)
#pragma unroll
    for (int j = 0; j < 4; j++) acc[i][j] = (f32x4){0.f, 0.f, 0.f, 0.f};

  // staging: thread t covers row t>>3 of a 64-row piece, physical 16B slot t&7;
  // global chunk pre-swizzled by (row&7) so LDS dest stays linear (rule #21).
  const int trow = tid >> 3;
  const int gch = ((tid & 7) ^ (trow & 7)) * 8;
  const short* Ag = Xb + (long)(m0 + trow) * 1024 + gch;
  const short* Bg = Wb + (long)(n0 + trow) * 1024 + gch;
  const int lo = tid * 8;  // shorts: wave-uniform base + lane*16B

  // fragment bases (shorts): row = (wseg*64 + f*16 + c), chunk = (kh*4+g)^(c&7)
  const int fA = (wm * 64 + c) * 64;
  const int fB = 8192 + (wn * 64 + c) * 64;
  const int ck0 = (g ^ (c & 7)) * 8;  // K-half 1: ck0 ^ 32

#define QKV_STG(bs, ko) do { \
    GLD_LDS16(Ag + (ko),              &lds[bs][lo]); \
    GLD_LDS16(Ag + (ko) + 64 * 1024,  &lds[bs][4096 + lo]); \
    GLD_LDS16(Bg + (ko),              &lds[bs][8192 + lo]); \
    GLD_LDS16(Bg + (ko) + 64 * 1024,  &lds[bs][12288 + lo]); \
    GLD_LDS16(Bg + (ko) + 128 * 1024, &lds[bs][16384 + lo]); \
    GLD_LDS16(Bg + (ko) + 192 * 1024, &lds[bs][20480 + lo]); \
  } while (0)

  // prologue: stage kt0+kt1; wait kt0 only (kt1's 6 stay in flight)
  QKV_STG(0, 0);
  QKV_STG(1, 64);
  asm volatile("s_waitcnt vmcnt(6)" ::: "memory");
  __builtin_amdgcn_s_barrier();

  bf16x8 fa[2][4], fb[2][4];
#pragma unroll
  for (int mf = 0; mf < 4; mf++) fa[0][mf] = *(const bf16x8*)&lds[0][fA + mf * 1024 + ck0];
#pragma unroll
  for (int nf = 0; nf < 4; nf++) fb[0][nf] = *(const bf16x8*)&lds[0][fB + nf * 1024 + ck0];

#pragma unroll
  for (int kt = 0; kt < 16; ++kt) {
    const short* Bf = &lds[kt % 3][0];
    // issue K-half-1 reads; delivery overlaps the half-0 MFMA cluster
#pragma unroll
    for (int mf = 0; mf < 4; mf++) fa[1][mf] = *(const bf16x8*)&Bf[fA + mf * 1024 + (ck0 ^ 32)];
#pragma unroll
    for (int nf = 0; nf < 4; nf++) fb[1][nf] = *(const bf16x8*)&Bf[fB + nf * 1024 + (ck0 ^ 32)];
    __builtin_amdgcn_sched_barrier(0);
    __builtin_amdgcn_s_setprio(1);
#pragma unroll
    for (int mf = 0; mf < 4; mf++)
#pragma unroll
      for (int nf = 0; nf < 4; nf++)
        acc[mf][nf] = __builtin_amdgcn_mfma_f32_16x16x32_bf16(fb[0][nf], fa[0][mf], acc[mf][nf], 0, 0, 0);
    __builtin_amdgcn_s_setprio(0);
    __builtin_amdgcn_sched_barrier(0);
    if (kt < 15) {
      // ONE rendezvous per K-tile: next buffer's 6 loads (issued a full iter ago)
      // must have landed; all waves are past their reads of buf[kt-1].
      asm volatile("s_waitcnt vmcnt(0)" ::: "memory");
      __builtin_amdgcn_s_barrier();
      if (kt < 14) QKV_STG((kt + 2) % 3, (kt + 2) * 64);
      const short* Bn = &lds[(kt + 1) % 3][0];
#pragma unroll
      for (int mf = 0; mf < 4; mf++) fa[0][mf] = *(const bf16x8*)&Bn[fA + mf * 1024 + ck0];
#pragma unroll
      for (int nf = 0; nf < 4; nf++) fb[0][nf] = *(const bf16x8*)&Bn[fB + nf * 1024 + ck0];
      __builtin_amdgcn_sched_barrier(0);
    }
    __builtin_amdgcn_s_setprio(1);
#pragma unroll
    for (int mf = 0; mf < 4; mf++)
#pragma unroll
      for (int nf = 0; nf < 4; nf++)
        acc[mf][nf] = __builtin_amdgcn_mfma_f32_16x16x32_bf16(fb[1][nf], fa[1][mf], acc[mf][nf], 0, 0, 0);
    __builtin_amdgcn_s_setprio(0);
  }
#undef QKV_STG

  // epilogue: lane owns token r (col=c), 4 consecutive channels (rows=g*4+reg)
  for (int jt = 0; jt < 4; jt++) {
    const int chan = n0 + wn * 64 + jt * 16 + g * 4;  // %4 == 0
    const int three = chan >> 10;
    const int hh = (chan >> 6) & 15;
    const int d = chan & 63;
    const float4 bq = *(const float4*)&bqkv[chan];
    for (int i = 0; i < 4; i++) {
      const int r = m0 + wm * 64 + i * 16 + c;
      const int l = r >> 3, b = r & 7;
      float v0 = acc[i][jt][0] + bq.x;
      float v1 = acc[i][jt][1] + bq.y;
      float v2 = acc[i][jt][2] + bq.z;
      float v3 = acc[i][jt][3] + bq.w;
      const long doff = ((long)(b * 16 + hh) * 1024 + l) * 64 + d;
      if (three == 2) {
        uint2 o = {pack2_bf16(v0, v1), pack2_bf16(v2, v3)};
        *(uint2*)&vbuf[doff] = o;
      } else {
        const float4 cs = *(const float4*)&cosT[l * 32 + (d & 31)];
        const float4 sn = *(const float4*)&sinT[l * 32 + (d & 31)];
        float e0 = v0 * cs.x - v1 * sn.x;
        float o0 = v1 * cs.y + v0 * sn.y;
        float e1 = v2 * cs.z - v3 * sn.z;
        float o1 = v3 * cs.w + v2 * sn.w;
        short* dst;
        if (three == 0) {
          const float S = 0.18033688011f;  // 1/sqrt(D) * log2(e)
          e0 *= S; o0 *= S; e1 *= S; o1 *= S;
          dst = qb;
        } else {
          dst = kbuf;
        }
        uint2 o = {pack2_bf16(e0, o0), pack2_bf16(e1, o1)};
        *(uint2*)&dst[doff] = o;
      }
    }
  }
}

// ---------------- V transpose: (B,H,L,D) -> (B,H,D,L) ----------------
__global__ __launch_bounds__(256) void transpose_v(const short* __restrict__ vbuf,
                                                   short* __restrict__ vTb) {
  __shared__ short T[64 * 72];
  const int bh = blockIdx.y;
  const int l0 = blockIdx.x * 64;
  const int t = threadIdx.x;
  const int row = t >> 3;
  const int cc = (t & 7) * 8;
  const short* src = vbuf + ((long)bh * 1024 + l0) * 64;
  for (int p = 0; p < 2; p++) {
    int lr = row + p * 32;
    *(bf16x8*)&T[lr * 72 + cc] = *(const bf16x8*)&src[(long)lr * 64 + cc];
  }
  __syncthreads();
  short* dst = vTb + (long)bh * 64 * 1024 + l0;
  for (int p = 0; p < 2; p++) {
    int d = row + p * 32;
    bf16x8 v;
    for (int j = 0; j < 8; j++) v[j] = T[(cc + j) * 72 + d];
    *(bf16x8*)&dst[(long)d * 1024 + cc] = v;
  }
}

// ---------------- flash attention v8 (unchanged) ----------------
__global__ __launch_bounds__(256, 5) void flash_attn(
    const short* __restrict__ qb, const short* __restrict__ kbuf,
    const short* __restrict__ vTb, const u64* __restrict__ maskb,
    short* __restrict__ attno) {
  __shared__ short K0[64 * 64], K1[64 * 64];
  __shared__ short V0[64 * 64], V1[64 * 64];
  const int t = threadIdx.x;
  const int wid = t >> 6, lane = t & 63;
  const int g = lane >> 4, c = lane & 15;
  const int bid = blockIdx.y * 16 + blockIdx.x;
  const int swz = (bid & 7) * 256 + (bid >> 3);
  const int q0 = (swz & 15) * 64;
  const int bh = swz >> 4;
  const int b = bh >> 4;
  const int h = bh & 15;
  const long qoff = (long)bh * 1024 * 64;
  const int qrow = q0 + wid * 16 + c;

  bf16x8 aq0, aq1;
  {
    const short* qp = qb + qoff + (long)qrow * 64;
    aq0 = *(const bf16x8*)(qp + g * 8);
    aq1 = *(const bf16x8*)(qp + 32 + g * 8);
  }

  f32x4 Od[4];
  for (int i = 0; i < 4; i++) Od[i] = (f32x4){0.f, 0.f, 0.f, 0.f};
  f32x4 Ld = (f32x4){0.f, 0.f, 0.f, 0.f};
  float m_run = -1e30f;

  bf16x8 avOnes8;
  {
    union { bf16x8 v; u32 u[4]; } av;
    u32 o1 = (c == 0) ? 0x3F803F80u : 0u;
    av.u[0] = av.u[1] = av.u[2] = av.u[3] = o1;
    avOnes8 = av.v;
  }

  const u64* mrow = maskb + ((long)b * 1024 + qrow) * 16;
  const short* Kg = kbuf + qoff;
  const short* Vg = vTb + qoff;

  const int l8 = lane >> 3, l7 = lane & 7;
  const int sr = wid * 16 + l8;
  const int sch = ((l7 ^ l8) & 7) * 8;
  const int r1 = wid * 16 + l8;
  const int r2 = r1 + 8;
  const int kp1 = (r1 & 32) | (((r1 & 15) >> 2) << 3) | (((r1 >> 4) & 1) << 2) | (r1 & 3);
  const int kp2 = (r2 & 32) | (((r2 & 15) >> 2) << 3) | (((r2 >> 4) & 1) << 2) | (r2 & 3);

  const int ck0 = g ^ (c & 7);
  const int kOff0 = c * 64 + ck0 * 8;
  const int kOff1 = c * 64 + (ck0 ^ 4) * 8;
  int vOff32[2];
  for (int kg = 0; kg < 2; kg++)
    vOff32[kg] = c * 64 + (((kg * 4 + g) ^ (c & 7)) * 8);

#define STAGE(KD, VD, ktn) do { \
    GLD_LDS16(Kg + (long)((ktn) + kp1) * 64 + sch,      &KD[(wid * 16) * 64]); \
    GLD_LDS16(Kg + (long)((ktn) + kp2) * 64 + sch,      &KD[(wid * 16 + 8) * 64]); \
    GLD_LDS16(Vg + (long)sr * 1024 + (ktn) + sch,       &VD[(wid * 16) * 64]); \
    GLD_LDS16(Vg + (long)(sr + 8) * 1024 + (ktn) + sch, &VD[(wid * 16 + 8) * 64]); \
  } while (0)

#define TILE(KB, VB, KP, VP, ki) do { \
    u64 mw = mrow[ki]; \
    __syncthreads(); \
    STAGE(KP, VP, (((ki) + 1) & 15) * 64); \
    f32x4 z[4]; \
    for (int nt = 0; nt < 4; nt++) { \
      bf16x8 bk0 = *(const bf16x8*)&KB[kOff0 + nt * 1024]; \
      bf16x8 bk1 = *(const bf16x8*)&KB[kOff1 + nt * 1024]; \
      f32x4 zz = (f32x4){0.f, 0.f, 0.f, 0.f}; \
      zz = __builtin_amdgcn_mfma_f32_16x16x32_bf16(bk0, aq0, zz, 0, 0, 0); \
      zz = __builtin_amdgcn_mfma_f32_16x16x32_bf16(bk1, aq1, zz, 0, 0, 0); \
      z[nt] = zz; \
    } \
    float mx = fmaxf(fmaxf(fmaxf(z[0][0], z[0][1]), fmaxf(z[0][2], z[0][3])), \
                     fmaxf(fmaxf(z[1][0], z[1][1]), fmaxf(z[1][2], z[1][3]))); \
    mx = fmaxf(mx, fmaxf(fmaxf(fmaxf(z[2][0], z[2][1]), fmaxf(z[2][2], z[2][3])), \
                         fmaxf(fmaxf(z[3][0], z[3][1]), fmaxf(z[3][2], z[3][3])))); \
    if (__ballot(mx > m_run + 8.f)) { \
      mx = fmaxf(mx, __shfl_xor(mx, 16, 64)); \
      mx = fmaxf(mx, __shfl_xor(mx, 32, 64)); \
      float mnew = fmaxf(m_run, mx); \
      float al = exp2_fast(m_run - mnew); \
      for (int dt = 0; dt < 4; dt++) { \
        Od[dt][0] *= al; Od[dt][1] *= al; Od[dt][2] *= al; Od[dt][3] *= al; \
      } \
      Ld[0] *= al; \
      m_run = mnew; \
    } \
    for (int kg = 0; kg < 2; kg++) { \
      union { bf16x8 v; u32 u[4]; } pu; \
      for (int ntp = 0; ntp < 2; ntp++) { \
        const int nt = kg * 2 + ntp; \
        u32 m4 = (u32)(mw >> (kg * 32 + g * 8 + ntp * 4)) & 0xFu; \
        u32 mlo = ((m4 & 1u) ? 0xFFFFu : 0u) | ((m4 & 2u) ? 0xFFFF0000u : 0u); \
        u32 mhi = ((m4 & 4u) ? 0xFFFFu : 0u) | ((m4 & 8u) ? 0xFFFF0000u : 0u); \
        float p0 = exp2_fast(z[nt][0] - m_run); \
        float p1 = exp2_fast(z[nt][1] - m_run); \
        float p2 = exp2_fast(z[nt][2] - m_run); \
        float p3 = exp2_fast(z[nt][3] - m_run); \
        pu.u[ntp * 2 + 0] = pack2_bf16(p0, p1) & mlo; \
        pu.u[ntp * 2 + 1] = pack2_bf16(p2, p3) & mhi; \
      } \
      Ld = __builtin_amdgcn_mfma_f32_16x16x32_bf16(avOnes8, pu.v, Ld, 0, 0, 0); \
      for (int dt = 0; dt < 4; dt++) { \
        bf16x8 av = *(const bf16x8*)&VB[vOff32[kg] + dt * 1024]; \
        Od[dt] = __builtin_amdgcn_mfma_f32_16x16x32_bf16(av, pu.v, Od[dt], 0, 0, 0); \
      } \
    } \
  } while (0)

  STAGE(K0, V0, 0);
  for (int ki = 0; ki < 16; ki += 2) {
    TILE(K0, V0, K1, V1, ki);
    TILE(K1, V1, K0, V0, ki + 1);
  }
#undef TILE
#undef STAGE

  float lsum = __shfl(Ld[0], c, 64);
  float inv = 1.f / lsum;
  long rbase = ((long)qrow * 8 + b) * 1024 + h * 64 + g * 4;
  for (int dt = 0; dt < 4; dt++) {
    union { bf16x4 v; u32 u[2]; } o;
    o.u[0] = pack2_bf16(Od[dt][0] * inv, Od[dt][1] * inv);
    o.u[1] = pack2_bf16(Od[dt][2] * inv, Od[dt][3] * inv);
    *(bf16x4*)&attno[rbase + dt * 16] = o.v;
  }
}

// ---------------- GEMM 2 v4: reg-dbuf pipeline, one barrier per K-tile ----------------
// Tile 128x128, BK=32, 3-buf LDS (48KB -> 3 blocks/CU). MFMA cluster split in two
// halves around the vmcnt+barrier so the stage-wait hides under compute; next-set
// ds_reads issued between the halves.
__global__ __launch_bounds__(256, 3) void gemm_out(
    const short* __restrict__ Ab, const short* __restrict__ Wob,
    const float* __restrict__ bo, float* __restrict__ out) {
  __shared__ short Ash[3][4096];
  __shared__ short Bsh[3][4096];
  const int tid = threadIdx.x;
  const int wid = tid >> 6, lane = tid & 63;
  const int g = lane >> 4, c = lane & 15;
  const int wm = wid >> 1, wn = wid & 1;
  const int bid = blockIdx.y * 8 + blockIdx.x;
  const int swz = (bid & 7) * 64 + (bid >> 3);
  const int m0 = (swz >> 3) * 128, n0 = (swz & 7) * 128;

  f32x4 acc[4][4];
#pragma unroll
  for (int i = 0; i < 4; i++)
#pragma unroll
    for (int j = 0; j < 4; j++) acc[i][j] = (f32x4){0.f, 0.f, 0.f, 0.f};

  const int srow = lane >> 2;
  const int scol = ((lane & 3) ^ ((lane >> 3) & 3)) * 8;
  const short* AgL = Ab + (long)(m0 + wid * 32 + srow) * 1024 + scol;
  const short* BgL = Wob + (long)(n0 + wid * 32 + srow) * 1024 + scol;
  const int dst0 = (wid * 32) * 32;
  const int dst1 = (wid * 32 + 16) * 32;
  const int ck = g ^ ((c >> 1) & 3);

#define OUT_STG(bs, ko) do { \
    GLD_LDS16(AgL + (ko), &Ash[bs][dst0]); \
    GLD_LDS16(AgL + (ko) + 16 * 1024, &Ash[bs][dst1]); \
    GLD_LDS16(BgL + (ko), &Bsh[bs][dst0]); \
    GLD_LDS16(BgL + (ko) + 16 * 1024, &Bsh[bs][dst1]); \
  } while (0)

  OUT_STG(0, 0);
  OUT_STG(1, 32);
  asm volatile("s_waitcnt vmcnt(4)" ::: "memory");
  __builtin_amdgcn_s_barrier();

  bf16x8 af[2][4], bfr[2][4];
#pragma unroll
  for (int i = 0; i < 4; i++)
    af[0][i] = *(const bf16x8*)&Ash[0][(wm * 64 + i * 16 + c) * 32 + ck * 8];
#pragma unroll
  for (int j = 0; j < 4; j++)
    bfr[0][j] = *(const bf16x8*)&Bsh[0][(wn * 64 + j * 16 + c) * 32 + ck * 8];

#pragma unroll
  for (int kt = 0; kt < 32; ++kt) {
    const int cur = kt & 1, nxt = cur ^ 1;
    __builtin_amdgcn_s_setprio(1);
#pragma unroll
    for (int i = 0; i < 2; i++)
#pragma unroll
      for (int j = 0; j < 4; j++)
        acc[i][j] = __builtin_amdgcn_mfma_f32_16x16x32_bf16(af[cur][i], bfr[cur][j], acc[i][j], 0, 0, 0);
    __builtin_amdgcn_s_setprio(0);
    __builtin_amdgcn_sched_barrier(0);
    if (kt < 31) {
      asm volatile("s_waitcnt vmcnt(0)" ::: "memory");
      __builtin_amdgcn_s_barrier();
      if (kt < 30) OUT_STG((kt + 2) % 3, (kt + 2) * 32);
      const int bn = (kt + 1) % 3;
#pragma unroll
      for (int i = 0; i < 4; i++)
        af[nxt][i] = *(const bf16x8*)&Ash[bn][(wm * 64 + i * 16 + c) * 32 + ck * 8];
#pragma unroll
      for (int j = 0; j < 4; j++)
        bfr[nxt][j] = *(const bf16x8*)&Bsh[bn][(wn * 64 + j * 16 + c) * 32 + ck * 8];
      __builtin_amdgcn_sched_barrier(0);
    }
    __builtin_amdgcn_s_setprio(1);
#pragma unroll
    for (int i = 2; i < 4; i++)
#pragma unroll
      for (int j = 0; j < 4; j++)
        acc[i][j] = __builtin_amdgcn_mfma_f32_16x16x32_bf16(af[cur][i], bfr[cur][j], acc[i][j], 0, 0, 0);
    __builtin_amdgcn_s_setprio(0);
  }
#undef OUT_STG

  for (int jt = 0; jt < 4; jt++) {
    const int j = n0 + wn * 64 + jt * 16 + c;
    const float bias = bo[j];
    for (int i = 0; i < 4; i++) {
      const int rbase = m0 + wm * 64 + i * 16 + g * 4;
      for (int reg = 0; reg < 4; reg++)
        out[(long)(rbase + reg) * 1024 + j] = acc[i][jt][reg] + bias;
    }
  }
}

// ---------------- launcher ----------------
extern "C" void kernel_launch(void* const* d_in, const int* in_sizes, int n_in,
                              void* d_out, int out_size, void* d_ws, size_t ws_size,
                              hipStream_t stream) {
  const float* hs = (const float*)d_in[0];
  const float* rpe = (const float*)d_in[1];
  const int* amask = (const int*)d_in[2];
  const float* Wqkv = (const float*)d_in[3];
  const float* bqkv = (const float*)d_in[4];
  const float* Wo = (const float*)d_in[5];
  const float* bo = (const float*)d_in[6];
  float* out = (float*)d_out;

  char* ws = (char*)d_ws;
  auto alloc = [&](size_t bytes) {
    char* p = ws;
    ws += (bytes + 255) & ~(size_t)255;
    return p;
  };
  short* Xb = (short*)alloc(8192LL * 1024 * 2);
  short* Wqkvb = (short*)alloc(3072LL * 1024 * 2);
  short* Wob = (short*)alloc(1024LL * 1024 * 2);
  float* cosT = (float*)alloc(1024 * 32 * 4);
  float* sinT = (float*)alloc(1024 * 32 * 4);
  u64* maskb = (u64*)alloc(8LL * 1024 * 16 * 8);
  short* qb = (short*)alloc(128LL * 1024 * 64 * 2);
  short* kbuf = (short*)alloc(128LL * 1024 * 64 * 2);
  short* vbuf = (short*)alloc(128LL * 1024 * 64 * 2);
  short* vTb = (short*)alloc(128LL * 1024 * 64 * 2);
  short* attno = (short*)alloc(8192LL * 1024 * 2);

  prep_all<<<45184, 256, 0, stream>>>(amask, maskb, hs, Wqkv, Wo, Xb, Wqkvb, Wob,
                                      rpe, cosT, sinT);
  gemm_qkv<<<dim3(12, 64), 512, 0, stream>>>(Xb, Wqkvb, bqkv, cosT, sinT, qb, kbuf, vbuf);
  transpose_v<<<dim3(16, 128), 256, 0, stream>>>(vbuf, vTb);
  flash_attn<<<dim3(16, 128), 256, 0, stream>>>(qb, kbuf, vTb, maskb, attno);
  gemm_out<<<dim3(8, 64), 256, 0, stream>>>(attno, Wob, bo, out);
}

// Round 6
// 286.298 us; speedup vs baseline: 1.2061x; 1.0630x over previous
//
#include <hip/hip_runtime.h>
#include <hip/hip_bf16.h>

typedef short bf16x8 __attribute__((ext_vector_type(8)));
typedef short bf16x4 __attribute__((ext_vector_type(4)));
typedef float f32x4 __attribute__((ext_vector_type(4)));
typedef unsigned int u32;
typedef unsigned long long u64;

#define GLD_LDS16(gp, lp) \
  __builtin_amdgcn_global_load_lds((const __attribute__((address_space(1))) u32*)(gp), \
                                   (__attribute__((address_space(3))) u32*)(lp), 16, 0, 0)

__device__ __forceinline__ short f2bf(float f) {
  u32 u = __builtin_bit_cast(u32, f);
  u = (u + 0x7fffu + ((u >> 16) & 1u)) >> 16;
  return (short)u;
}

// gfx950 has no cvt_pk_bf16 builtin (m240) -- hardware op via inline asm.
__device__ __forceinline__ u32 pack2_bf16(float a, float b) {
#if __has_builtin(__builtin_amdgcn_cvt_pk_bf16_f32)
  typedef __bf16 bf16v2 __attribute__((ext_vector_type(2)));
  bf16v2 r = __builtin_amdgcn_cvt_pk_bf16_f32(a, b);
  return __builtin_bit_cast(u32, r);
#else
  u32 r;
  asm("v_cvt_pk_bf16_f32 %0, %1, %2" : "=v"(r) : "v"(a), "v"(b));
  return r;
#endif
}

__device__ __forceinline__ float exp2_fast(float x) {
#if __has_builtin(__builtin_amdgcn_exp2f)
  return __builtin_amdgcn_exp2f(x);
#else
  return exp2f(x);
#endif
}

// duplicate two mask bytes of src into bf16 halves: sel [b,b,b',b'] -> 0xFFFF/0 pairs
__device__ __forceinline__ u32 bytemask2(u32 src, u32 sel) {
  u32 r;
  asm("v_perm_b32 %0, %1, %1, %2" : "=v"(r) : "v"(src), "v"(sel));
  return r;
}

// ---------------- fused prep: mask byte-table (8192) + cvt (12288) + rope (128) ----
__global__ __launch_bounds__(256) void prep_all(
    const int* __restrict__ m, unsigned char* __restrict__ maskt,
    const float* __restrict__ hs, const float* __restrict__ wqkv,
    const float* __restrict__ wo, short* __restrict__ xb,
    short* __restrict__ wqkvb, short* __restrict__ wob,
    const float* __restrict__ rpe, float* __restrict__ cosT,
    float* __restrict__ sinT) {
  int b = blockIdx.x;
  if (b < 8192) {
    // t[b][q][k] = m[b][q][k] ? 0xFF : 0  (8 MB, L3-resident)
    int i = b * 1024 + threadIdx.x * 4;
    int4 v = *(const int4*)(m + i);
    uchar4 o;
    o.x = v.x ? 0xFFu : 0u;
    o.y = v.y ? 0xFFu : 0u;
    o.z = v.z ? 0xFFu : 0u;
    o.w = v.w ? 0xFFu : 0u;
    *(uchar4*)(maskt + i) = o;
    return;
  }
  b -= 8192;
  if (b < 12288) {
    const float* in;
    short* out;
    int base;
    if (b < 8192) {
      in = hs; out = xb; base = b * 1024;
    } else if (b < 8192 + 3072) {
      in = wqkv; out = wqkvb; base = (b - 8192) * 1024;
    } else {
      in = wo; out = wob; base = (b - 11264) * 1024;
    }
    int i = base + threadIdx.x * 4;
    float4 v = *(const float4*)(in + i);
    short4 o;
    o.x = f2bf(v.x); o.y = f2bf(v.y); o.z = f2bf(v.z); o.w = f2bf(v.w);
    *(short4*)(out + i) = o;
    return;
  }
  b -= 12288;
  int i = b * 256 + threadIdx.x;  // 32768 = 1024*32
  float v = rpe[i];
  cosT[i] = cosf(v);
  sinT[i] = sinf(v);
}

// ---------------- GEMM 1 v5 (unchanged from round 5) ----------------
__global__ __launch_bounds__(512, 2) void gemm_qkv(
    const short* __restrict__ Xb, const short* __restrict__ Wb,
    const float* __restrict__ bqkv, const float* __restrict__ cosT,
    const float* __restrict__ sinT, short* __restrict__ qb,
    short* __restrict__ kbuf, short* __restrict__ vbuf) {
  __shared__ short lds[3][24576];  // [buf][A:128x64 | B:256x64]
  const int tid = threadIdx.x;
  const int wid = tid >> 6, lane = tid & 63;
  const int g = lane >> 4, c = lane & 15;
  const int wm = wid >> 2, wn = wid & 3;
  const int bid = blockIdx.y * 12 + blockIdx.x;
  const int swz = (bid & 7) * 96 + (bid >> 3);
  const int m0 = (swz / 12) * 128, n0 = (swz % 12) * 256;

  f32x4 acc[4][4];
#pragma unroll
  for (int i = 0; i < 4; i++)
#pragma unroll
    for (int j = 0; j < 4; j++) acc[i][j] = (f32x4){0.f, 0.f, 0.f, 0.f};

  const int trow = tid >> 3;
  const int gch = ((tid & 7) ^ (trow & 7)) * 8;
  const short* Ag = Xb + (long)(m0 + trow) * 1024 + gch;
  const short* Bg = Wb + (long)(n0 + trow) * 1024 + gch;
  const int lo = tid * 8;

  const int fA = (wm * 64 + c) * 64;
  const int fB = 8192 + (wn * 64 + c) * 64;
  const int ck0 = (g ^ (c & 7)) * 8;

#define QKV_STG(bs, ko) do { \
    GLD_LDS16(Ag + (ko),              &lds[bs][lo]); \
    GLD_LDS16(Ag + (ko) + 64 * 1024,  &lds[bs][4096 + lo]); \
    GLD_LDS16(Bg + (ko),              &lds[bs][8192 + lo]); \
    GLD_LDS16(Bg + (ko) + 64 * 1024,  &lds[bs][12288 + lo]); \
    GLD_LDS16(Bg + (ko) + 128 * 1024, &lds[bs][16384 + lo]); \
    GLD_LDS16(Bg + (ko) + 192 * 1024, &lds[bs][20480 + lo]); \
  } while (0)

  QKV_STG(0, 0);
  QKV_STG(1, 64);
  asm volatile("s_waitcnt vmcnt(6)" ::: "memory");
  __builtin_amdgcn_s_barrier();

  bf16x8 fa[2][4], fb[2][4];
#pragma unroll
  for (int mf = 0; mf < 4; mf++) fa[0][mf] = *(const bf16x8*)&lds[0][fA + mf * 1024 + ck0];
#pragma unroll
  for (int nf = 0; nf < 4; nf++) fb[0][nf] = *(const bf16x8*)&lds[0][fB + nf * 1024 + ck0];

#pragma unroll
  for (int kt = 0; kt < 16; ++kt) {
    const short* Bf = &lds[kt % 3][0];
#pragma unroll
    for (int mf = 0; mf < 4; mf++) fa[1][mf] = *(const bf16x8*)&Bf[fA + mf * 1024 + (ck0 ^ 32)];
#pragma unroll
    for (int nf = 0; nf < 4; nf++) fb[1][nf] = *(const bf16x8*)&Bf[fB + nf * 1024 + (ck0 ^ 32)];
    __builtin_amdgcn_sched_barrier(0);
    __builtin_amdgcn_s_setprio(1);
#pragma unroll
    for (int mf = 0; mf < 4; mf++)
#pragma unroll
      for (int nf = 0; nf < 4; nf++)
        acc[mf][nf] = __builtin_amdgcn_mfma_f32_16x16x32_bf16(fb[0][nf], fa[0][mf], acc[mf][nf], 0, 0, 0);
    __builtin_amdgcn_s_setprio(0);
    __builtin_amdgcn_sched_barrier(0);
    if (kt < 15) {
      asm volatile("s_waitcnt vmcnt(0)" ::: "memory");
      __builtin_amdgcn_s_barrier();
      if (kt < 14) QKV_STG((kt + 2) % 3, (kt + 2) * 64);
      const short* Bn = &lds[(kt + 1) % 3][0];
#pragma unroll
      for (int mf = 0; mf < 4; mf++) fa[0][mf] = *(const bf16x8*)&Bn[fA + mf * 1024 + ck0];
#pragma unroll
      for (int nf = 0; nf < 4; nf++) fb[0][nf] = *(const bf16x8*)&Bn[fB + nf * 1024 + ck0];
      __builtin_amdgcn_sched_barrier(0);
    }
    __builtin_amdgcn_s_setprio(1);
#pragma unroll
    for (int mf = 0; mf < 4; mf++)
#pragma unroll
      for (int nf = 0; nf < 4; nf++)
        acc[mf][nf] = __builtin_amdgcn_mfma_f32_16x16x32_bf16(fb[1][nf], fa[1][mf], acc[mf][nf], 0, 0, 0);
    __builtin_amdgcn_s_setprio(0);
  }
#undef QKV_STG

  for (int jt = 0; jt < 4; jt++) {
    const int chan = n0 + wn * 64 + jt * 16 + g * 4;
    const int three = chan >> 10;
    const int hh = (chan >> 6) & 15;
    const int d = chan & 63;
    const float4 bq = *(const float4*)&bqkv[chan];
    for (int i = 0; i < 4; i++) {
      const int r = m0 + wm * 64 + i * 16 + c;
      const int l = r >> 3, b = r & 7;
      float v0 = acc[i][jt][0] + bq.x;
      float v1 = acc[i][jt][1] + bq.y;
      float v2 = acc[i][jt][2] + bq.z;
      float v3 = acc[i][jt][3] + bq.w;
      const long doff = ((long)(b * 16 + hh) * 1024 + l) * 64 + d;
      if (three == 2) {
        uint2 o = {pack2_bf16(v0, v1), pack2_bf16(v2, v3)};
        *(uint2*)&vbuf[doff] = o;
      } else {
        const float4 cs = *(const float4*)&cosT[l * 32 + (d & 31)];
        const float4 sn = *(const float4*)&sinT[l * 32 + (d & 31)];
        float e0 = v0 * cs.x - v1 * sn.x;
        float o0 = v1 * cs.y + v0 * sn.y;
        float e1 = v2 * cs.z - v3 * sn.z;
        float o1 = v3 * cs.w + v2 * sn.w;
        short* dst;
        if (three == 0) {
          const float S = 0.18033688011f;  // 1/sqrt(D) * log2(e)
          e0 *= S; o0 *= S; e1 *= S; o1 *= S;
          dst = qb;
        } else {
          dst = kbuf;
        }
        uint2 o = {pack2_bf16(e0, o0), pack2_bf16(e1, o1)};
        *(uint2*)&dst[doff] = o;
      }
    }
  }
}

// ---------------- V transpose: (B,H,L,D) -> (B,H,D,L) ----------------
__global__ __launch_bounds__(256) void transpose_v(const short* __restrict__ vbuf,
                                                   short* __restrict__ vTb) {
  __shared__ short T[64 * 72];
  const int bh = blockIdx.y;
  const int l0 = blockIdx.x * 64;
  const int t = threadIdx.x;
  const int row = t >> 3;
  const int cc = (t & 7) * 8;
  const short* src = vbuf + ((long)bh * 1024 + l0) * 64;
  for (int p = 0; p < 2; p++) {
    int lr = row + p * 32;
    *(bf16x8*)&T[lr * 72 + cc] = *(const bf16x8*)&src[(long)lr * 64 + cc];
  }
  __syncthreads();
  short* dst = vTb + (long)bh * 64 * 1024 + l0;
  for (int p = 0; p < 2; p++) {
    int d = row + p * 32;
    bf16x8 v;
    for (int j = 0; j < 8; j++) v[j] = T[(cc + j) * 72 + d];
    *(bf16x8*)&dst[(long)d * 1024 + cc] = v;
  }
}

// ---------------- flash attention v9 ----------------
// vs v8: (1) mask expansion replaced by precomputed byte-table reads (2x8B/tile)
// + v_perm byte-duplication (8 ops) -- removes ~50 VALU ops/tile/lane;
// (2) T5 setprio(1) around both MFMA clusters; (3) PV restructured: build both
// P fragments (VALU), then one 10-MFMA cluster.
__global__ __launch_bounds__(256, 5) void flash_attn(
    const short* __restrict__ qb, const short* __restrict__ kbuf,
    const short* __restrict__ vTb, const unsigned char* __restrict__ maskt,
    short* __restrict__ attno) {
  __shared__ short K0[64 * 64], K1[64 * 64];
  __shared__ short V0[64 * 64], V1[64 * 64];
  const int t = threadIdx.x;
  const int wid = t >> 6, lane = t & 63;
  const int g = lane >> 4, c = lane & 15;
  const int bid = blockIdx.y * 16 + blockIdx.x;
  const int swz = (bid & 7) * 256 + (bid >> 3);
  const int q0 = (swz & 15) * 64;
  const int bh = swz >> 4;
  const int b = bh >> 4;
  const int h = bh & 15;
  const long qoff = (long)bh * 1024 * 64;
  const int qrow = q0 + wid * 16 + c;

  const u32 SEL01 = 0x01010000u;  // dst bytes = [b0,b0,b1,b1]
  const u32 SEL23 = 0x03030202u;  // dst bytes = [b2,b2,b3,b3]

  bf16x8 aq0, aq1;
  {
    const short* qp = qb + qoff + (long)qrow * 64;
    aq0 = *(const bf16x8*)(qp + g * 8);
    aq1 = *(const bf16x8*)(qp + 32 + g * 8);
  }

  f32x4 Od[4];
  for (int i = 0; i < 4; i++) Od[i] = (f32x4){0.f, 0.f, 0.f, 0.f};
  f32x4 Ld = (f32x4){0.f, 0.f, 0.f, 0.f};
  float m_run = -1e30f;

  bf16x8 avOnes8;
  {
    union { bf16x8 v; u32 u[4]; } av;
    u32 o1 = (c == 0) ? 0x3F803F80u : 0u;
    av.u[0] = av.u[1] = av.u[2] = av.u[3] = o1;
    avOnes8 = av.v;
  }

  // per-lane mask row: keys [kg*32 + g*8 .. +8) of each 64-key tile
  const unsigned char* mrow8 = maskt + ((long)b * 1024 + qrow) * 1024 + g * 8;
  const short* Kg = kbuf + qoff;
  const short* Vg = vTb + qoff;

  const int l8 = lane >> 3, l7 = lane & 7;
  const int sr = wid * 16 + l8;
  const int sch = ((l7 ^ l8) & 7) * 8;
  const int r1 = wid * 16 + l8;
  const int r2 = r1 + 8;
  const int kp1 = (r1 & 32) | (((r1 & 15) >> 2) << 3) | (((r1 >> 4) & 1) << 2) | (r1 & 3);
  const int kp2 = (r2 & 32) | (((r2 & 15) >> 2) << 3) | (((r2 >> 4) & 1) << 2) | (r2 & 3);

  const int ck0 = g ^ (c & 7);
  const int kOff0 = c * 64 + ck0 * 8;
  const int kOff1 = c * 64 + (ck0 ^ 4) * 8;
  int vOff32[2];
  for (int kg = 0; kg < 2; kg++)
    vOff32[kg] = c * 64 + (((kg * 4 + g) ^ (c & 7)) * 8);

#define STAGE(KD, VD, ktn) do { \
    GLD_LDS16(Kg + (long)((ktn) + kp1) * 64 + sch,      &KD[(wid * 16) * 64]); \
    GLD_LDS16(Kg + (long)((ktn) + kp2) * 64 + sch,      &KD[(wid * 16 + 8) * 64]); \
    GLD_LDS16(Vg + (long)sr * 1024 + (ktn) + sch,       &VD[(wid * 16) * 64]); \
    GLD_LDS16(Vg + (long)(sr + 8) * 1024 + (ktn) + sch, &VD[(wid * 16 + 8) * 64]); \
  } while (0)

#define TILE(KB, VB, KP, VP, ki) do { \
    __syncthreads(); /* drains prefetch issued a full tile of compute ago */ \
    STAGE(KP, VP, (((ki) + 1) & 15) * 64); \
    /* mask bytes: L2/L3-resident; latency hides under QK^T below */ \
    const uint2 w0 = *(const uint2*)&mrow8[(ki) * 64]; \
    const uint2 w1 = *(const uint2*)&mrow8[(ki) * 64 + 32]; \
    f32x4 z[4]; \
    __builtin_amdgcn_s_setprio(1); \
    for (int nt = 0; nt < 4; nt++) { \
      bf16x8 bk0 = *(const bf16x8*)&KB[kOff0 + nt * 1024]; \
      bf16x8 bk1 = *(const bf16x8*)&KB[kOff1 + nt * 1024]; \
      f32x4 zz = (f32x4){0.f, 0.f, 0.f, 0.f}; \
      zz = __builtin_amdgcn_mfma_f32_16x16x32_bf16(bk0, aq0, zz, 0, 0, 0); \
      zz = __builtin_amdgcn_mfma_f32_16x16x32_bf16(bk1, aq1, zz, 0, 0, 0); \
      z[nt] = zz; \
    } \
    __builtin_amdgcn_s_setprio(0); \
    float mx = fmaxf(fmaxf(fmaxf(z[0][0], z[0][1]), fmaxf(z[0][2], z[0][3])), \
                     fmaxf(fmaxf(z[1][0], z[1][1]), fmaxf(z[1][2], z[1][3]))); \
    mx = fmaxf(mx, fmaxf(fmaxf(fmaxf(z[2][0], z[2][1]), fmaxf(z[2][2], z[2][3])), \
                         fmaxf(fmaxf(z[3][0], z[3][1]), fmaxf(z[3][2], z[3][3])))); \
    if (__ballot(mx > m_run + 8.f)) { /* rare after warm-up (T13) */ \
      mx = fmaxf(mx, __shfl_xor(mx, 16, 64)); \
      mx = fmaxf(mx, __shfl_xor(mx, 32, 64)); \
      float mnew = fmaxf(m_run, mx); \
      float al = exp2_fast(m_run - mnew); \
      for (int dt = 0; dt < 4; dt++) { \
        Od[dt][0] *= al; Od[dt][1] *= al; Od[dt][2] *= al; Od[dt][3] *= al; \
      } \
      Ld[0] *= al; \
      m_run = mnew; \
    } \
    union { bf16x8 v; u32 u[4]; } puA, puB; \
    { \
      float p0 = exp2_fast(z[0][0] - m_run), p1 = exp2_fast(z[0][1] - m_run); \
      float p2 = exp2_fast(z[0][2] - m_run), p3 = exp2_fast(z[0][3] - m_run); \
      float p4 = exp2_fast(z[1][0] - m_run), p5 = exp2_fast(z[1][1] - m_run); \
      float p6 = exp2_fast(z[1][2] - m_run), p7 = exp2_fast(z[1][3] - m_run); \
      puA.u[0] = pack2_bf16(p0, p1) & bytemask2(w0.x, SEL01); \
      puA.u[1] = pack2_bf16(p2, p3) & bytemask2(w0.x, SEL23); \
      puA.u[2] = pack2_bf16(p4, p5) & bytemask2(w0.y, SEL01); \
      puA.u[3] = pack2_bf16(p6, p7) & bytemask2(w0.y, SEL23); \
    } \
    { \
      float p0 = exp2_fast(z[2][0] - m_run), p1 = exp2_fast(z[2][1] - m_run); \
      float p2 = exp2_fast(z[2][2] - m_run), p3 = exp2_fast(z[2][3] - m_run); \
      float p4 = exp2_fast(z[3][0] - m_run), p5 = exp2_fast(z[3][1] - m_run); \
      float p6 = exp2_fast(z[3][2] - m_run), p7 = exp2_fast(z[3][3] - m_run); \
      puB.u[0] = pack2_bf16(p0, p1) & bytemask2(w1.x, SEL01); \
      puB.u[1] = pack2_bf16(p2, p3) & bytemask2(w1.x, SEL23); \
      puB.u[2] = pack2_bf16(p4, p5) & bytemask2(w1.y, SEL01); \
      puB.u[3] = pack2_bf16(p6, p7) & bytemask2(w1.y, SEL23); \
    } \
    __builtin_amdgcn_s_setprio(1); \
    Ld = __builtin_amdgcn_mfma_f32_16x16x32_bf16(avOnes8, puA.v, Ld, 0, 0, 0); \
    for (int dt = 0; dt < 4; dt++) { \
      bf16x8 av = *(const bf16x8*)&VB[vOff32[0] + dt * 1024]; \
      Od[dt] = __builtin_amdgcn_mfma_f32_16x16x32_bf16(av, puA.v, Od[dt], 0, 0, 0); \
    } \
    Ld = __builtin_amdgcn_mfma_f32_16x16x32_bf16(avOnes8, puB.v, Ld, 0, 0, 0); \
    for (int dt = 0; dt < 4; dt++) { \
      bf16x8 av = *(const bf16x8*)&VB[vOff32[1] + dt * 1024]; \
      Od[dt] = __builtin_amdgcn_mfma_f32_16x16x32_bf16(av, puB.v, Od[dt], 0, 0, 0); \
    } \
    __builtin_amdgcn_s_setprio(0); \
  } while (0)

  STAGE(K0, V0, 0);
  for (int ki = 0; ki < 16; ki += 2) {
    TILE(K0, V0, K1, V1, ki);
    TILE(K1, V1, K0, V0, ki + 1);
  }
#undef TILE
#undef STAGE

  float lsum = __shfl(Ld[0], c, 64);
  float inv = 1.f / lsum;
  long rbase = ((long)qrow * 8 + b) * 1024 + h * 64 + g * 4;
  for (int dt = 0; dt < 4; dt++) {
    union { bf16x4 v; u32 u[2]; } o;
    o.u[0] = pack2_bf16(Od[dt][0] * inv, Od[dt][1] * inv);
    o.u[1] = pack2_bf16(Od[dt][2] * inv, Od[dt][3] * inv);
    *(bf16x4*)&attno[rbase + dt * 16] = o.v;
  }
}

// ---------------- GEMM 2 v4 (unchanged from round 5) ----------------
__global__ __launch_bounds__(256, 3) void gemm_out(
    const short* __restrict__ Ab, const short* __restrict__ Wob,
    const float* __restrict__ bo, float* __restrict__ out) {
  __shared__ short Ash[3][4096];
  __shared__ short Bsh[3][4096];
  const int tid = threadIdx.x;
  const int wid = tid >> 6, lane = tid & 63;
  const int g = lane >> 4, c = lane & 15;
  const int wm = wid >> 1, wn = wid & 1;
  const int bid = blockIdx.y * 8 + blockIdx.x;
  const int swz = (bid & 7) * 64 + (bid >> 3);
  const int m0 = (swz >> 3) * 128, n0 = (swz & 7) * 128;

  f32x4 acc[4][4];
#pragma unroll
  for (int i = 0; i < 4; i++)
#pragma unroll
    for (int j = 0; j < 4; j++) acc[i][j] = (f32x4){0.f, 0.f, 0.f, 0.f};

  const int srow = lane >> 2;
  const int scol = ((lane & 3) ^ ((lane >> 3) & 3)) * 8;
  const short* AgL = Ab + (long)(m0 + wid * 32 + srow) * 1024 + scol;
  const short* BgL = Wob + (long)(n0 + wid * 32 + srow) * 1024 + scol;
  const int dst0 = (wid * 32) * 32;
  const int dst1 = (wid * 32 + 16) * 32;
  const int ck = g ^ ((c >> 1) & 3);

#define OUT_STG(bs, ko) do { \
    GLD_LDS16(AgL + (ko), &Ash[bs][dst0]); \
    GLD_LDS16(AgL + (ko) + 16 * 1024, &Ash[bs][dst1]); \
    GLD_LDS16(BgL + (ko), &Bsh[bs][dst0]); \
    GLD_LDS16(BgL + (ko) + 16 * 1024, &Bsh[bs][dst1]); \
  } while (0)

  OUT_STG(0, 0);
  OUT_STG(1, 32);
  asm volatile("s_waitcnt vmcnt(4)" ::: "memory");
  __builtin_amdgcn_s_barrier();

  bf16x8 af[2][4], bfr[2][4];
#pragma unroll
  for (int i = 0; i < 4; i++)
    af[0][i] = *(const bf16x8*)&Ash[0][(wm * 64 + i * 16 + c) * 32 + ck * 8];
#pragma unroll
  for (int j = 0; j < 4; j++)
    bfr[0][j] = *(const bf16x8*)&Bsh[0][(wn * 64 + j * 16 + c) * 32 + ck * 8];

#pragma unroll
  for (int kt = 0; kt < 32; ++kt) {
    const int cur = kt & 1, nxt = cur ^ 1;
    __builtin_amdgcn_s_setprio(1);
#pragma unroll
    for (int i = 0; i < 2; i++)
#pragma unroll
      for (int j = 0; j < 4; j++)
        acc[i][j] = __builtin_amdgcn_mfma_f32_16x16x32_bf16(af[cur][i], bfr[cur][j], acc[i][j], 0, 0, 0);
    __builtin_amdgcn_s_setprio(0);
    __builtin_amdgcn_sched_barrier(0);
    if (kt < 31) {
      asm volatile("s_waitcnt vmcnt(0)" ::: "memory");
      __builtin_amdgcn_s_barrier();
      if (kt < 30) OUT_STG((kt + 2) % 3, (kt + 2) * 32);
      const int bn = (kt + 1) % 3;
#pragma unroll
      for (int i = 0; i < 4; i++)
        af[nxt][i] = *(const bf16x8*)&Ash[bn][(wm * 64 + i * 16 + c) * 32 + ck * 8];
#pragma unroll
      for (int j = 0; j < 4; j++)
        bfr[nxt][j] = *(const bf16x8*)&Bsh[bn][(wn * 64 + j * 16 + c) * 32 + ck * 8];
      __builtin_amdgcn_sched_barrier(0);
    }
    __builtin_amdgcn_s_setprio(1);
#pragma unroll
    for (int i = 2; i < 4; i++)
#pragma unroll
      for (int j = 0; j < 4; j++)
        acc[i][j] = __builtin_amdgcn_mfma_f32_16x16x32_bf16(af[cur][i], bfr[cur][j], acc[i][j], 0, 0, 0);
    __builtin_amdgcn_s_setprio(0);
  }
#undef OUT_STG

  for (int jt = 0; jt < 4; jt++) {
    const int j = n0 + wn * 64 + jt * 16 + c;
    const float bias = bo[j];
    for (int i = 0; i < 4; i++) {
      const int rbase = m0 + wm * 64 + i * 16 + g * 4;
      for (int reg = 0; reg < 4; reg++)
        out[(long)(rbase + reg) * 1024 + j] = acc[i][jt][reg] + bias;
    }
  }
}

// ---------------- launcher ----------------
extern "C" void kernel_launch(void* const* d_in, const int* in_sizes, int n_in,
                              void* d_out, int out_size, void* d_ws, size_t ws_size,
                              hipStream_t stream) {
  const float* hs = (const float*)d_in[0];
  const float* rpe = (const float*)d_in[1];
  const int* amask = (const int*)d_in[2];
  const float* Wqkv = (const float*)d_in[3];
  const float* bqkv = (const float*)d_in[4];
  const float* Wo = (const float*)d_in[5];
  const float* bo = (const float*)d_in[6];
  float* out = (float*)d_out;

  char* ws = (char*)d_ws;
  auto alloc = [&](size_t bytes) {
    char* p = ws;
    ws += (bytes + 255) & ~(size_t)255;
    return p;
  };
  short* Xb = (short*)alloc(8192LL * 1024 * 2);
  short* Wqkvb = (short*)alloc(3072LL * 1024 * 2);
  short* Wob = (short*)alloc(1024LL * 1024 * 2);
  float* cosT = (float*)alloc(1024 * 32 * 4);
  float* sinT = (float*)alloc(1024 * 32 * 4);
  unsigned char* maskt = (unsigned char*)alloc(8LL * 1024 * 1024);  // byte mask table
  short* qb = (short*)alloc(128LL * 1024 * 64 * 2);
  short* kbuf = (short*)alloc(128LL * 1024 * 64 * 2);
  short* vbuf = (short*)alloc(128LL * 1024 * 64 * 2);
  short* vTb = (short*)alloc(128LL * 1024 * 64 * 2);
  short* attno = (short*)alloc(8192LL * 1024 * 2);

  prep_all<<<20608, 256, 0, stream>>>(amask, maskt, hs, Wqkv, Wo, Xb, Wqkvb, Wob,
                                      rpe, cosT, sinT);
  gemm_qkv<<<dim3(12, 64), 512, 0, stream>>>(Xb, Wqkvb, bqkv, cosT, sinT, qb, kbuf, vbuf);
  transpose_v<<<dim3(16, 128), 256, 0, stream>>>(vbuf, vTb);
  flash_attn<<<dim3(16, 128), 256, 0, stream>>>(qb, kbuf, vTb, maskt, attno);
  gemm_out<<<dim3(8, 64), 256, 0, stream>>>(attno, Wob, bo, out);
}